// Round 4
// baseline (289.083 us; speedup 1.0000x reference)
//
#include <hip/hip_runtime.h>
#include <hip/hip_bf16.h>
#include <math.h>

using bf16x8 = __attribute__((ext_vector_type(8))) __bf16;
using bf16x4 = __attribute__((ext_vector_type(4))) __bf16;
using f32x4  = __attribute__((ext_vector_type(4))) float;
using u32x4  = __attribute__((ext_vector_type(4))) unsigned;

static constexpr int S_ = 2048;
static constexpr float SCALE_L2E = 0.125f * 1.44269504088896340736f; // 1/sqrt(64) * log2(e)

__device__ __forceinline__ void gload16(const void* g, void* lds) {
    __builtin_amdgcn_global_load_lds((const __attribute__((address_space(1))) void*)g,
                                     (__attribute__((address_space(3))) void*)lds, 16, 0, 0);
}

__device__ __forceinline__ unsigned pk2(float a, float b) {
    unsigned short lo = __builtin_bit_cast(unsigned short, (__bf16)a);
    unsigned short hi = __builtin_bit_cast(unsigned short, (__bf16)b);
    return (unsigned)lo | ((unsigned)hi << 16);
}

__global__ void cast_f32_bf16(const float* __restrict__ src, __bf16* __restrict__ dst, int n4) {
    int i = blockIdx.x * blockDim.x + threadIdx.x;
    if (i < n4) {
        float4 v = reinterpret_cast<const float4*>(src)[i];
        bf16x4 o = { (__bf16)v.x, (__bf16)v.y, (__bf16)v.z, (__bf16)v.w };
        reinterpret_cast<bf16x4*>(dst)[i] = o;
    }
}

// C[m,n] = sum_k A[m,k] * Bt[n,k]   (A: MxK row-major bf16, Bt: NxK row-major bf16)
// EPI 0: QKV scatter epilogue (Q pre-scaled by 1/sqrt(d)*log2e; K row-major;
//        V transposed per head with within-64-tile column permutation psi) + bias select
// EPI 1: fp32 output epilogue + bias
template <int EPI>
__global__ __launch_bounds__(256) void gemm_bt(
    const __bf16* __restrict__ A, const __bf16* __restrict__ Bt,
    const float* __restrict__ b0, const float* __restrict__ b1, const float* __restrict__ b2,
    __bf16* __restrict__ Qo, __bf16* __restrict__ Ko, __bf16* __restrict__ Vo,
    float* __restrict__ Fo, int K) {
    __shared__ __align__(16) __bf16 As[128 * 32];
    __shared__ __align__(16) __bf16 Bs[128 * 32];
    const int t = threadIdx.x, l = t & 63, w = t >> 6;
    const int m0 = blockIdx.y * 128, n0 = blockIdx.x * 128;
    const int wm = (w >> 1) * 64, wn = (w & 1) * 64;
    f32x4 acc[4][4] = {};

    const int row0 = t >> 2, cw0 = t & 3; // chunk t: 16B chunks, 4 per 32-elem row
    const __bf16* Ag0 = A + (size_t)(m0 + row0) * K + cw0 * 8;
    const __bf16* Ag1 = A + (size_t)(m0 + row0 + 64) * K + cw0 * 8;
    const __bf16* Bg0 = Bt + (size_t)(n0 + row0) * K + cw0 * 8;
    const __bf16* Bg1 = Bt + (size_t)(n0 + row0 + 64) * K + cw0 * 8;
    __bf16* Al0 = &As[(w * 64) * 8];
    __bf16* Al1 = &As[(w * 64 + 256) * 8];
    __bf16* Bl0 = &Bs[(w * 64) * 8];
    __bf16* Bl1 = &Bs[(w * 64 + 256) * 8];

    for (int k0 = 0; k0 < K; k0 += 32) {
        gload16(Ag0 + k0, Al0);
        gload16(Ag1 + k0, Al1);
        gload16(Bg0 + k0, Bl0);
        gload16(Bg1 + k0, Bl1);
        __syncthreads();
        bf16x8 af[4], bf[4];
#pragma unroll
        for (int i = 0; i < 4; ++i)
            af[i] = *reinterpret_cast<const bf16x8*>(&As[(wm + i * 16 + (l & 15)) * 32 + (l >> 4) * 8]);
#pragma unroll
        for (int j = 0; j < 4; ++j)
            bf[j] = *reinterpret_cast<const bf16x8*>(&Bs[(wn + j * 16 + (l & 15)) * 32 + (l >> 4) * 8]);
#pragma unroll
        for (int i = 0; i < 4; ++i)
#pragma unroll
            for (int j = 0; j < 4; ++j)
                acc[i][j] = __builtin_amdgcn_mfma_f32_16x16x32_bf16(af[i], bf[j], acc[i][j], 0, 0, 0);
        __syncthreads();
    }

    if (EPI == 0) {
        const int cls = n0 >> 10; // 0=Q 1=K 2=V (N=3072, tile 128 never straddles)
        const float* bias = (cls == 0) ? b0 : ((cls == 1) ? b1 : b2);
#pragma unroll
        for (int j = 0; j < 4; ++j) {
            const int e = n0 + wn + j * 16 + (l & 15);
            const int eh = e & 1023;
            const int h = eh >> 6, hd = eh & 63;
            const float bv = bias[eh];
#pragma unroll
            for (int i = 0; i < 4; ++i)
#pragma unroll
                for (int r = 0; r < 4; ++r) {
                    const int m = m0 + wm + i * 16 + ((l >> 4) << 2) + r;
                    const int b = m >> 11, s = m & 2047;
                    float v = acc[i][j][r] + bv;
                    if (cls == 0) {
                        v *= SCALE_L2E; // fold softmax scale into Q (fp32, pre-cast)
                        Qo[((size_t)(b * 16 + h) * 2048 + s) * 64 + hd] = (__bf16)v;
                    } else if (cls == 1) {
                        Ko[((size_t)(b * 16 + h) * 2048 + s) * 64 + hd] = (__bf16)v;
                    } else {
                        // V transposed, with within-64-tile column permutation psi so that
                        // attn's PV B-fragment is lane-local (zero-exchange): kv -> psi
                        const int st = s & 63;
                        const int quad = (st & 31) >> 2;
                        const int psi = (st & 32) | ((quad & 3) << 3) | ((quad >> 2) << 2) | (st & 3);
                        Vo[((size_t)(b * 16 + h) * 64 + hd) * 2048 + (s & ~63) + psi] = (__bf16)v;
                    }
                }
        }
    } else {
#pragma unroll
        for (int j = 0; j < 4; ++j) {
            const int e = n0 + wn + j * 16 + (l & 15);
            const float bv = b0[e];
#pragma unroll
            for (int i = 0; i < 4; ++i)
#pragma unroll
                for (int r = 0; r < 4; ++r) {
                    const int m = m0 + wm + i * 16 + ((l >> 4) << 2) + r;
                    Fo[(size_t)m * 1024 + e] = acc[i][j][r] + bv;
                }
        }
    }
}

// Flash attention, causal, SWAPPED-operand form: S^T = mfma(K,Q), O^T = mfma(VT,P^T).
// Each lane owns ONE q row (q = qw + (l&15)). P never touches LDS: the PV B-fragment
// k-order is chosen so each lane's own packed P words ARE the fragment (V columns are
// pre-permuted by psi at the producer). K/V double-buffered, counted-vmcnt pipeline.
__global__ __launch_bounds__(512) void attn_fwd(
    const __bf16* __restrict__ Qb, const __bf16* __restrict__ Kb,
    const __bf16* __restrict__ VTb, __bf16* __restrict__ Ob) {
    __shared__ __align__(16) __bf16 Ks[2][64 * 64];
    __shared__ __align__(16) __bf16 Vs[2][64 * 64];
    const int t = threadIdx.x, l = t & 63, w = t >> 6;
    const int qt = (int)gridDim.x - 1 - (int)blockIdx.x; // reversed: heavy blocks first
    const int bh = blockIdx.y;
    const int qw = qt * 128 + w * 16;
    const int qg = qw + (l & 15); // this lane's q row

    const __bf16* Qg = Qb + (size_t)bh * S_ * 64;
    const __bf16* Kg = Kb + (size_t)bh * S_ * 64;
    const __bf16* Vg = VTb + (size_t)bh * 64 * S_;

    bf16x8 qf[2];
    qf[0] = *reinterpret_cast<const bf16x8*>(Qg + (size_t)qg * 64 + (l >> 4) * 8);
    qf[1] = *reinterpret_cast<const bf16x8*>(Qg + (size_t)qg * 64 + 32 + (l >> 4) * 8);

    f32x4 o_acc[4] = {};
    float m_r = -INFINITY; // running max for q = qg (log2 domain)
    float l_r = 0.f;       // running denom

    // staging: 512 16B chunks each for K and VT; dest linear, source pre-swizzled (involution)
    const int srow = t >> 3, sc = t & 7;
    const __bf16* Ksrc = Kg + (size_t)srow * 64 + ((sc ^ (srow & 7)) * 8);
    const __bf16* Vsrc = Vg + (size_t)srow * S_ + ((sc ^ (srow & 7)) * 8);
    __bf16* Kd0 = &Ks[0][(w * 64) * 8];
    __bf16* Kd1 = &Ks[1][(w * 64) * 8];
    __bf16* Vd0 = &Vs[0][(w * 64) * 8];
    __bf16* Vd1 = &Vs[1][(w * 64) * 8];

    const int ktmax = 2 * qt + 1;
    gload16(Ksrc, Kd0);
    gload16(Vsrc, Vd0);
    int cur = 0;
    for (int kt = 0; kt <= ktmax; ++kt) {
        if (kt < ktmax) {
            gload16(Ksrc + (size_t)(kt + 1) * 4096, (cur == 0) ? Kd1 : Kd0);
            gload16(Vsrc + (kt + 1) * 64, (cur == 0) ? Vd1 : Vd0);
            asm volatile("s_waitcnt vmcnt(2)" ::: "memory"); // tile kt complete, kt+1 in flight
        } else {
            asm volatile("s_waitcnt vmcnt(0)" ::: "memory");
        }
        __builtin_amdgcn_s_barrier();
        const char* kb = (cur == 0) ? (const char*)Ks[0] : (const char*)Ks[1];
        const char* vb = (cur == 0) ? (const char*)Vs[0] : (const char*)Vs[1];
        if (kt * 64 <= qw + 15) { // wave has at least one unmasked row
            // S^T = K Q^T : lane gets S[q = l&15][kv = j*16 + (l>>4)*4 + r]
            f32x4 sa[4] = {};
            __builtin_amdgcn_s_setprio(1);
#pragma unroll
            for (int kk = 0; kk < 2; ++kk) {
#pragma unroll
                for (int j = 0; j < 4; ++j) {
                    const int row = j * 16 + (l & 15);
                    int byt = row * 128 + (kk * 32 + (l >> 4) * 8) * 2;
                    byt ^= (row & 7) << 4;
                    bf16x8 kf = *reinterpret_cast<const bf16x8*>(kb + byt);
                    sa[j] = __builtin_amdgcn_mfma_f32_16x16x32_bf16(kf, qf[kk], sa[j], 0, 0, 0);
                }
            }
            __builtin_amdgcn_s_setprio(0);
            // causal mask (scale already folded into Q)
            float p[4][4];
            const bool bnd = (kt * 64 + 63) > qw; // only boundary tiles need masking
#pragma unroll
            for (int j = 0; j < 4; ++j) {
                const int kv0 = kt * 64 + j * 16 + ((l >> 4) << 2);
#pragma unroll
                for (int r = 0; r < 4; ++r) {
                    float x = sa[j][r];
                    if (bnd && (kv0 + r) > qg) x = -INFINITY;
                    p[j][r] = x;
                }
            }
            // row max: in-register tree + 2 shuffles
            float mt;
            {
                float a0 = fmaxf(fmaxf(p[0][0], p[0][1]), fmaxf(p[0][2], p[0][3]));
                float a1 = fmaxf(fmaxf(p[1][0], p[1][1]), fmaxf(p[1][2], p[1][3]));
                float a2 = fmaxf(fmaxf(p[2][0], p[2][1]), fmaxf(p[2][2], p[2][3]));
                float a3 = fmaxf(fmaxf(p[3][0], p[3][1]), fmaxf(p[3][2], p[3][3]));
                mt = fmaxf(fmaxf(a0, a1), fmaxf(a2, a3));
                mt = fmaxf(mt, __shfl_xor(mt, 16));
                mt = fmaxf(mt, __shfl_xor(mt, 32));
            }
            // defer-max (T13): skip rescale while growth <= 8 (values bounded by 2^8)
            if (!__all(mt - m_r <= 8.0f)) {
                const float mn = fmaxf(m_r, mt);
                const float al = exp2f(m_r - mn);
                m_r = mn;
                l_r *= al;
#pragma unroll
                for (int j = 0; j < 4; ++j)
#pragma unroll
                    for (int r = 0; r < 4; ++r) o_acc[j][r] *= al;
            }
            float sum = 0.f;
#pragma unroll
            for (int j = 0; j < 4; ++j)
#pragma unroll
                for (int r = 0; r < 4; ++r) {
                    const float e = exp2f(p[j][r] - m_r);
                    p[j][r] = e;
                    sum += e;
                }
            sum += __shfl_xor(sum, 16);
            sum += __shfl_xor(sum, 32);
            l_r += sum;
            // O^T += VT P^T : P fragment is lane-local (V columns psi-permuted at producer).
            // B-frag(kk) words = (pk(p[2kk][0],p[2kk][1]), pk(p[2kk][2],p[2kk][3]),
            //                     pk(p[2kk+1][0],p[2kk+1][1]), pk(p[2kk+1][2],p[2kk+1][3]))
            __builtin_amdgcn_s_setprio(1);
#pragma unroll
            for (int kk = 0; kk < 2; ++kk) {
                u32x4 pwv = { pk2(p[2 * kk][0], p[2 * kk][1]), pk2(p[2 * kk][2], p[2 * kk][3]),
                              pk2(p[2 * kk + 1][0], p[2 * kk + 1][1]), pk2(p[2 * kk + 1][2], p[2 * kk + 1][3]) };
                bf16x8 pf = __builtin_bit_cast(bf16x8, pwv);
#pragma unroll
                for (int j = 0; j < 4; ++j) {
                    const int hd = j * 16 + (l & 15);
                    int vb2 = hd * 128 + (kk * 32 + (l >> 4) * 8) * 2;
                    vb2 ^= (hd & 7) << 4;
                    bf16x8 vf = *reinterpret_cast<const bf16x8*>(vb + vb2);
                    o_acc[j] = __builtin_amdgcn_mfma_f32_16x16x32_bf16(vf, pf, o_acc[j], 0, 0, 0);
                }
            }
            __builtin_amdgcn_s_setprio(0);
        }
        __builtin_amdgcn_s_barrier(); // all reads of buf[cur] done before it is re-staged
        cur ^= 1;
    }
    const int b = bh >> 4, h = bh & 15;
    const float inv = 1.0f / l_r;
#pragma unroll
    for (int j = 0; j < 4; ++j) {
        bf16x4 ov = { (__bf16)(o_acc[j][0] * inv), (__bf16)(o_acc[j][1] * inv),
                      (__bf16)(o_acc[j][2] * inv), (__bf16)(o_acc[j][3] * inv) };
        const int hd = j * 16 + ((l >> 4) << 2);
        *reinterpret_cast<bf16x4*>(&Ob[(size_t)(b * 2048 + qg) * 1024 + h * 64 + hd]) = ov;
    }
}

extern "C" void kernel_launch(void* const* d_in, const int* in_sizes, int n_in,
                              void* d_out, int out_size, void* d_ws, size_t ws_size,
                              hipStream_t stream) {
    const float* x  = (const float*)d_in[0];
    const float* wq = (const float*)d_in[2];
    const float* bq = (const float*)d_in[3];
    const float* wk = (const float*)d_in[4];
    const float* bk = (const float*)d_in[5];
    const float* wv = (const float*)d_in[6];
    const float* bv = (const float*)d_in[7];
    const float* wo = (const float*)d_in[8];
    const float* bo = (const float*)d_in[9];
    float* out = (float*)d_out;

    char* ws = (char*)d_ws;
    __bf16* xb   = (__bf16*)(ws);                 // 8192x1024        = 16,777,216 B
    __bf16* wqkv = (__bf16*)(ws + 16777216);      // 3072x1024        =  6,291,456 B
    __bf16* wob  = (__bf16*)(ws + 23068672);      // 1024x1024        =  2,097,152 B
    __bf16* Qb   = (__bf16*)(ws + 25165824);      // 64x2048x64       = 16,777,216 B
    __bf16* Kb   = (__bf16*)(ws + 41943040);      // 64x2048x64       = 16,777,216 B
    __bf16* VTb  = (__bf16*)(ws + 58720256);      // 64x64x2048       = 16,777,216 B
    __bf16* Ob   = (__bf16*)(ws + 75497472);      // 8192x1024        = 16,777,216 B

    cast_f32_bf16<<<8192, 256, 0, stream>>>(x, xb, 2097152);
    cast_f32_bf16<<<1024, 256, 0, stream>>>(wq, wqkv, 262144);
    cast_f32_bf16<<<1024, 256, 0, stream>>>(wk, wqkv + 1048576, 262144);
    cast_f32_bf16<<<1024, 256, 0, stream>>>(wv, wqkv + 2097152, 262144);
    cast_f32_bf16<<<1024, 256, 0, stream>>>(wo, wob, 262144);

    gemm_bt<0><<<dim3(24, 64), 256, 0, stream>>>(xb, wqkv, bq, bk, bv, Qb, Kb, VTb, nullptr, 1024);
    attn_fwd<<<dim3(16, 64), 512, 0, stream>>>(Qb, Kb, VTb, Ob);
    gemm_bt<1><<<dim3(8, 64), 256, 0, stream>>>(Ob, wob, bo, nullptr, nullptr, nullptr, nullptr, nullptr, out, 1024);
}

// Round 5
// 229.127 us; speedup vs baseline: 1.2617x; 1.2617x over previous
//
#include <hip/hip_runtime.h>
#include <hip/hip_bf16.h>
#include <math.h>

using bf16x8 = __attribute__((ext_vector_type(8))) __bf16;
using bf16x4 = __attribute__((ext_vector_type(4))) __bf16;
using f32x4  = __attribute__((ext_vector_type(4))) float;
using u32x4  = __attribute__((ext_vector_type(4))) unsigned;

static constexpr int S_ = 2048;
static constexpr float SCALE_L2E = 0.125f * 1.44269504088896340736f; // 1/sqrt(64) * log2(e)

__device__ __forceinline__ void gload16(const void* g, void* lds) {
    __builtin_amdgcn_global_load_lds((const __attribute__((address_space(1))) void*)g,
                                     (__attribute__((address_space(3))) void*)lds, 16, 0, 0);
}

__device__ __forceinline__ unsigned pk2(float a, float b) {
    unsigned short lo = __builtin_bit_cast(unsigned short, (__bf16)a);
    unsigned short hi = __builtin_bit_cast(unsigned short, (__bf16)b);
    return (unsigned)lo | ((unsigned)hi << 16);
}

__global__ void cast_f32_bf16(const float* __restrict__ src, __bf16* __restrict__ dst, int n4) {
    int i = blockIdx.x * blockDim.x + threadIdx.x;
    if (i < n4) {
        float4 v = reinterpret_cast<const float4*>(src)[i];
        bf16x4 o = { (__bf16)v.x, (__bf16)v.y, (__bf16)v.z, (__bf16)v.w };
        reinterpret_cast<bf16x4*>(dst)[i] = o;
    }
}

// C[m,n] = sum_k A[m,k] * Bt[n,k]   (A: MxK row-major bf16, Bt: NxK row-major bf16)
// EPI 0: QKV scatter epilogue (Q pre-scaled by 1/sqrt(d)*log2e; K row-major;
//        V transposed per head with within-64-tile column permutation psi) + bias select
// EPI 1: fp32 output epilogue + bias
template <int EPI>
__global__ __launch_bounds__(256) void gemm_bt(
    const __bf16* __restrict__ A, const __bf16* __restrict__ Bt,
    const float* __restrict__ b0, const float* __restrict__ b1, const float* __restrict__ b2,
    __bf16* __restrict__ Qo, __bf16* __restrict__ Ko, __bf16* __restrict__ Vo,
    float* __restrict__ Fo, int K) {
    __shared__ __align__(16) __bf16 As[128 * 32];
    __shared__ __align__(16) __bf16 Bs[128 * 32];
    const int t = threadIdx.x, l = t & 63, w = t >> 6;
    const int m0 = blockIdx.y * 128, n0 = blockIdx.x * 128;
    const int wm = (w >> 1) * 64, wn = (w & 1) * 64;
    f32x4 acc[4][4] = {};

    const int row0 = t >> 2, cw0 = t & 3; // chunk t: 16B chunks, 4 per 32-elem row
    const __bf16* Ag0 = A + (size_t)(m0 + row0) * K + cw0 * 8;
    const __bf16* Ag1 = A + (size_t)(m0 + row0 + 64) * K + cw0 * 8;
    const __bf16* Bg0 = Bt + (size_t)(n0 + row0) * K + cw0 * 8;
    const __bf16* Bg1 = Bt + (size_t)(n0 + row0 + 64) * K + cw0 * 8;
    __bf16* Al0 = &As[(w * 64) * 8];
    __bf16* Al1 = &As[(w * 64 + 256) * 8];
    __bf16* Bl0 = &Bs[(w * 64) * 8];
    __bf16* Bl1 = &Bs[(w * 64 + 256) * 8];

    for (int k0 = 0; k0 < K; k0 += 32) {
        gload16(Ag0 + k0, Al0);
        gload16(Ag1 + k0, Al1);
        gload16(Bg0 + k0, Bl0);
        gload16(Bg1 + k0, Bl1);
        __syncthreads();
        bf16x8 af[4], bf[4];
#pragma unroll
        for (int i = 0; i < 4; ++i)
            af[i] = *reinterpret_cast<const bf16x8*>(&As[(wm + i * 16 + (l & 15)) * 32 + (l >> 4) * 8]);
#pragma unroll
        for (int j = 0; j < 4; ++j)
            bf[j] = *reinterpret_cast<const bf16x8*>(&Bs[(wn + j * 16 + (l & 15)) * 32 + (l >> 4) * 8]);
#pragma unroll
        for (int i = 0; i < 4; ++i)
#pragma unroll
            for (int j = 0; j < 4; ++j)
                acc[i][j] = __builtin_amdgcn_mfma_f32_16x16x32_bf16(af[i], bf[j], acc[i][j], 0, 0, 0);
        __syncthreads();
    }

    if (EPI == 0) {
        const int cls = n0 >> 10; // 0=Q 1=K 2=V (N=3072, tile 128 never straddles)
        const float* bias = (cls == 0) ? b0 : ((cls == 1) ? b1 : b2);
#pragma unroll
        for (int j = 0; j < 4; ++j) {
            const int e = n0 + wn + j * 16 + (l & 15);
            const int eh = e & 1023;
            const int h = eh >> 6, hd = eh & 63;
            const float bv = bias[eh];
#pragma unroll
            for (int i = 0; i < 4; ++i)
#pragma unroll
                for (int r = 0; r < 4; ++r) {
                    const int m = m0 + wm + i * 16 + ((l >> 4) << 2) + r;
                    const int b = m >> 11, s = m & 2047;
                    float v = acc[i][j][r] + bv;
                    if (cls == 0) {
                        v *= SCALE_L2E; // fold softmax scale into Q (fp32, pre-cast)
                        Qo[((size_t)(b * 16 + h) * 2048 + s) * 64 + hd] = (__bf16)v;
                    } else if (cls == 1) {
                        Ko[((size_t)(b * 16 + h) * 2048 + s) * 64 + hd] = (__bf16)v;
                    } else {
                        // V transposed, with within-64-tile column permutation psi so that
                        // attn's PV B-fragment is lane-local (zero-exchange): kv -> psi
                        const int st = s & 63;
                        const int quad = (st & 31) >> 2;
                        const int psi = (st & 32) | ((quad & 3) << 3) | ((quad >> 2) << 2) | (st & 3);
                        Vo[((size_t)(b * 16 + h) * 64 + hd) * 2048 + (s & ~63) + psi] = (__bf16)v;
                    }
                }
        }
    } else {
#pragma unroll
        for (int j = 0; j < 4; ++j) {
            const int e = n0 + wn + j * 16 + (l & 15);
            const float bv = b0[e];
#pragma unroll
            for (int i = 0; i < 4; ++i)
#pragma unroll
                for (int r = 0; r < 4; ++r) {
                    const int m = m0 + wm + i * 16 + ((l >> 4) << 2) + r;
                    Fo[(size_t)m * 1024 + e] = acc[i][j][r] + bv;
                }
        }
    }
}

// Flash attention, causal, SWAPPED-operand form: S^T = mfma(K,Q), O^T = mfma(VT,P^T).
// Each lane owns ONE q row. P never touches LDS (V columns psi-permuted at producer).
// CAUSAL PAIRING: block x handles strips qt = 15-x (heavy, first) and qt = x (light):
// (2(15-x)+2) + (2x+2) = 34 tiles for EVERY block -> perfectly uniform grid of 512
// blocks (2/CU resident, 16 waves/CU steady) with no straggler CUs.
__global__ __launch_bounds__(512) void attn_fwd(
    const __bf16* __restrict__ Qb, const __bf16* __restrict__ Kb,
    const __bf16* __restrict__ VTb, __bf16* __restrict__ Ob) {
    __shared__ __align__(16) __bf16 Ks[2][64 * 64];
    __shared__ __align__(16) __bf16 Vs[2][64 * 64];
    const int t = threadIdx.x, l = t & 63, w = t >> 6;
    const int bh = blockIdx.y;
    const int b = bh >> 4, h = bh & 15;

    const __bf16* Qg = Qb + (size_t)bh * S_ * 64;
    const __bf16* Kg = Kb + (size_t)bh * S_ * 64;
    const __bf16* Vg = VTb + (size_t)bh * 64 * S_;

    // staging: 512 16B chunks each for K and VT; dest linear, source pre-swizzled (involution)
    const int srow = t >> 3, sc = t & 7;
    const __bf16* Ksrc = Kg + (size_t)srow * 64 + ((sc ^ (srow & 7)) * 8);
    const __bf16* Vsrc = Vg + (size_t)srow * S_ + ((sc ^ (srow & 7)) * 8);
    __bf16* Kd0 = &Ks[0][(w * 64) * 8];
    __bf16* Kd1 = &Ks[1][(w * 64) * 8];
    __bf16* Vd0 = &Vs[0][(w * 64) * 8];
    __bf16* Vd1 = &Vs[1][(w * 64) * 8];

#pragma unroll 1
    for (int sidx = 0; sidx < 2; ++sidx) {
        const int qt = (sidx == 0) ? (15 - (int)blockIdx.x) : (int)blockIdx.x;
        const int qw = qt * 128 + w * 16;
        const int qg = qw + (l & 15); // this lane's q row

        bf16x8 qf[2];
        qf[0] = *reinterpret_cast<const bf16x8*>(Qg + (size_t)qg * 64 + (l >> 4) * 8);
        qf[1] = *reinterpret_cast<const bf16x8*>(Qg + (size_t)qg * 64 + 32 + (l >> 4) * 8);

        f32x4 o_acc[4] = {};
        float m_r = -INFINITY; // running max (log2 domain)
        float l_r = 0.f;       // running denom

        const int ktmax = 2 * qt + 1;
        gload16(Ksrc, Kd0);
        gload16(Vsrc, Vd0);
        int cur = 0;
        for (int kt = 0; kt <= ktmax; ++kt) {
            if (kt < ktmax) {
                gload16(Ksrc + (size_t)(kt + 1) * 4096, (cur == 0) ? Kd1 : Kd0);
                gload16(Vsrc + (kt + 1) * 64, (cur == 0) ? Vd1 : Vd0);
                asm volatile("s_waitcnt vmcnt(2)" ::: "memory"); // tile kt done, kt+1 in flight
            } else {
                asm volatile("s_waitcnt vmcnt(0)" ::: "memory");
            }
            __builtin_amdgcn_s_barrier();
            const char* kb = (cur == 0) ? (const char*)Ks[0] : (const char*)Ks[1];
            const char* vb = (cur == 0) ? (const char*)Vs[0] : (const char*)Vs[1];
            if (kt * 64 <= qw + 15) { // wave has at least one unmasked row
                // S^T = K Q^T : lane gets S[q = l&15][kv = j*16 + (l>>4)*4 + r]
                f32x4 sa[4] = {};
                __builtin_amdgcn_s_setprio(1);
#pragma unroll
                for (int kk = 0; kk < 2; ++kk) {
#pragma unroll
                    for (int j = 0; j < 4; ++j) {
                        const int row = j * 16 + (l & 15);
                        int byt = row * 128 + (kk * 32 + (l >> 4) * 8) * 2;
                        byt ^= (row & 7) << 4;
                        bf16x8 kf = *reinterpret_cast<const bf16x8*>(kb + byt);
                        sa[j] = __builtin_amdgcn_mfma_f32_16x16x32_bf16(kf, qf[kk], sa[j], 0, 0, 0);
                    }
                }
                __builtin_amdgcn_s_setprio(0);
                // causal mask (scale already folded into Q)
                float p[4][4];
                const bool bnd = (kt * 64 + 63) > qw; // only boundary tiles need masking
#pragma unroll
                for (int j = 0; j < 4; ++j) {
                    const int kv0 = kt * 64 + j * 16 + ((l >> 4) << 2);
#pragma unroll
                    for (int r = 0; r < 4; ++r) {
                        float x = sa[j][r];
                        if (bnd && (kv0 + r) > qg) x = -INFINITY;
                        p[j][r] = x;
                    }
                }
                // row max: in-register tree + 2 shuffles
                float mt;
                {
                    float a0 = fmaxf(fmaxf(p[0][0], p[0][1]), fmaxf(p[0][2], p[0][3]));
                    float a1 = fmaxf(fmaxf(p[1][0], p[1][1]), fmaxf(p[1][2], p[1][3]));
                    float a2 = fmaxf(fmaxf(p[2][0], p[2][1]), fmaxf(p[2][2], p[2][3]));
                    float a3 = fmaxf(fmaxf(p[3][0], p[3][1]), fmaxf(p[3][2], p[3][3]));
                    mt = fmaxf(fmaxf(a0, a1), fmaxf(a2, a3));
                    mt = fmaxf(mt, __shfl_xor(mt, 16));
                    mt = fmaxf(mt, __shfl_xor(mt, 32));
                }
                // defer-max (T13): skip rescale while growth <= 8 (values bounded by 2^8)
                if (!__all(mt - m_r <= 8.0f)) {
                    const float mn = fmaxf(m_r, mt);
                    const float al = exp2f(m_r - mn);
                    m_r = mn;
                    l_r *= al;
#pragma unroll
                    for (int j = 0; j < 4; ++j)
#pragma unroll
                        for (int r = 0; r < 4; ++r) o_acc[j][r] *= al;
                }
                float sum = 0.f;
#pragma unroll
                for (int j = 0; j < 4; ++j)
#pragma unroll
                    for (int r = 0; r < 4; ++r) {
                        const float e = exp2f(p[j][r] - m_r);
                        p[j][r] = e;
                        sum += e;
                    }
                sum += __shfl_xor(sum, 16);
                sum += __shfl_xor(sum, 32);
                l_r += sum;
                // O^T += VT P^T : P fragment is lane-local (V columns psi-permuted at producer)
                __builtin_amdgcn_s_setprio(1);
#pragma unroll
                for (int kk = 0; kk < 2; ++kk) {
                    u32x4 pwv = { pk2(p[2 * kk][0], p[2 * kk][1]), pk2(p[2 * kk][2], p[2 * kk][3]),
                                  pk2(p[2 * kk + 1][0], p[2 * kk + 1][1]), pk2(p[2 * kk + 1][2], p[2 * kk + 1][3]) };
                    bf16x8 pf = __builtin_bit_cast(bf16x8, pwv);
#pragma unroll
                    for (int j = 0; j < 4; ++j) {
                        const int hd = j * 16 + (l & 15);
                        int vb2 = hd * 128 + (kk * 32 + (l >> 4) * 8) * 2;
                        vb2 ^= (hd & 7) << 4;
                        bf16x8 vf = *reinterpret_cast<const bf16x8*>(vb + vb2);
                        o_acc[j] = __builtin_amdgcn_mfma_f32_16x16x32_bf16(vf, pf, o_acc[j], 0, 0, 0);
                    }
                }
                __builtin_amdgcn_s_setprio(0);
            }
            __builtin_amdgcn_s_barrier(); // all reads of buf[cur] done before it is re-staged
            cur ^= 1;
        }
        const float inv = 1.0f / l_r;
#pragma unroll
        for (int j = 0; j < 4; ++j) {
            bf16x4 ov = { (__bf16)(o_acc[j][0] * inv), (__bf16)(o_acc[j][1] * inv),
                          (__bf16)(o_acc[j][2] * inv), (__bf16)(o_acc[j][3] * inv) };
            const int hd = j * 16 + ((l >> 4) << 2);
            *reinterpret_cast<bf16x4*>(&Ob[(size_t)(b * 2048 + qg) * 1024 + h * 64 + hd]) = ov;
        }
    }
}

extern "C" void kernel_launch(void* const* d_in, const int* in_sizes, int n_in,
                              void* d_out, int out_size, void* d_ws, size_t ws_size,
                              hipStream_t stream) {
    const float* x  = (const float*)d_in[0];
    const float* wq = (const float*)d_in[2];
    const float* bq = (const float*)d_in[3];
    const float* wk = (const float*)d_in[4];
    const float* bk = (const float*)d_in[5];
    const float* wv = (const float*)d_in[6];
    const float* bv = (const float*)d_in[7];
    const float* wo = (const float*)d_in[8];
    const float* bo = (const float*)d_in[9];
    float* out = (float*)d_out;

    char* ws = (char*)d_ws;
    __bf16* xb   = (__bf16*)(ws);                 // 8192x1024        = 16,777,216 B
    __bf16* wqkv = (__bf16*)(ws + 16777216);      // 3072x1024        =  6,291,456 B
    __bf16* wob  = (__bf16*)(ws + 23068672);      // 1024x1024        =  2,097,152 B
    __bf16* Qb   = (__bf16*)(ws + 25165824);      // 64x2048x64       = 16,777,216 B
    __bf16* Kb   = (__bf16*)(ws + 41943040);      // 64x2048x64       = 16,777,216 B
    __bf16* VTb  = (__bf16*)(ws + 58720256);      // 64x64x2048       = 16,777,216 B
    __bf16* Ob   = (__bf16*)(ws + 75497472);      // 8192x1024        = 16,777,216 B

    cast_f32_bf16<<<8192, 256, 0, stream>>>(x, xb, 2097152);
    cast_f32_bf16<<<1024, 256, 0, stream>>>(wq, wqkv, 262144);
    cast_f32_bf16<<<1024, 256, 0, stream>>>(wk, wqkv + 1048576, 262144);
    cast_f32_bf16<<<1024, 256, 0, stream>>>(wv, wqkv + 2097152, 262144);
    cast_f32_bf16<<<1024, 256, 0, stream>>>(wo, wob, 262144);

    gemm_bt<0><<<dim3(24, 64), 256, 0, stream>>>(xb, wqkv, bq, bk, bv, Qb, Kb, VTb, nullptr, 1024);
    attn_fwd<<<dim3(8, 64), 512, 0, stream>>>(Qb, Kb, VTb, Ob);
    gemm_bt<1><<<dim3(8, 64), 256, 0, stream>>>(Ob, wob, bo, nullptr, nullptr, nullptr, nullptr, nullptr, out, 1024);
}

// Round 6
// 195.748 us; speedup vs baseline: 1.4768x; 1.1705x over previous
//
#include <hip/hip_runtime.h>
#include <hip/hip_bf16.h>
#include <math.h>

using bf16x8 = __attribute__((ext_vector_type(8))) __bf16;
using bf16x4 = __attribute__((ext_vector_type(4))) __bf16;
using f32x4  = __attribute__((ext_vector_type(4))) float;
using u32x4  = __attribute__((ext_vector_type(4))) unsigned;

static constexpr int S_ = 2048;
static constexpr float SCALE_L2E = 0.125f * 1.44269504088896340736f; // 1/sqrt(64) * log2(e)

__device__ __forceinline__ void gload16(const void* g, void* lds) {
    __builtin_amdgcn_global_load_lds((const __attribute__((address_space(1))) void*)g,
                                     (__attribute__((address_space(3))) void*)lds, 16, 0, 0);
}

__device__ __forceinline__ unsigned pk2(float a, float b) {
    unsigned short lo = __builtin_bit_cast(unsigned short, (__bf16)a);
    unsigned short hi = __builtin_bit_cast(unsigned short, (__bf16)b);
    return (unsigned)lo | ((unsigned)hi << 16);
}

__global__ void cast_f32_bf16(const float* __restrict__ src, __bf16* __restrict__ dst, int n4) {
    int i = blockIdx.x * blockDim.x + threadIdx.x;
    if (i < n4) {
        float4 v = reinterpret_cast<const float4*>(src)[i];
        bf16x4 o = { (__bf16)v.x, (__bf16)v.y, (__bf16)v.z, (__bf16)v.w };
        reinterpret_cast<bf16x4*>(dst)[i] = o;
    }
}

// C[m,n] = sum_k A[m,k] * Bt[n,k]   (A: MxK row-major bf16, Bt: NxK row-major bf16)
// 128x128 tile, BK=32, 3-deep LDS pipeline with counted vmcnt (stage k+2, wait vmcnt(8)),
// chunk-XOR LDS swizzle (pre-swizzled global source + swizzled ds_read: 8-way -> 2-way free).
// EPI 0: QKV epilogue. Q pre-scaled by 1/sqrt(d)*log2e, K row-major per head;
//        V transposed per head WITH psi column-permutation, written COALESCED via an
//        LDS transpose (reuses the 48KB staging LDS after the K-loop).
// EPI 1: fp32 output epilogue + bias
template <int EPI>
__global__ __launch_bounds__(256) void gemm_bt(
    const __bf16* __restrict__ A, const __bf16* __restrict__ Bt,
    const float* __restrict__ b0, const float* __restrict__ b1, const float* __restrict__ b2,
    __bf16* __restrict__ Qo, __bf16* __restrict__ Ko, __bf16* __restrict__ Vo,
    float* __restrict__ Fo, int K) {
    __shared__ __align__(16) __bf16 LDS_[3][2][4096]; // [buf][A/B][128 rows x 32 cols], 48KB
    const int t = threadIdx.x, l = t & 63, w = t >> 6;
    const int m0 = blockIdx.y * 128, n0 = blockIdx.x * 128;
    const int wm = (w >> 1) * 64, wn = (w & 1) * 64;
    f32x4 acc[4][4] = {};

    // staging: thread t stages rows (t>>2) and (t>>2)+64, 16B chunk (t&3), source
    // pre-swizzled by chunk ^= (row>>1)&3 (involution; LDS dest stays linear)
    const int row0 = t >> 2, cw0 = t & 3;
    const int gc = cw0 ^ ((row0 >> 1) & 3);
    const __bf16* Ag0 = A + (size_t)(m0 + row0) * K + gc * 8;
    const __bf16* Ag1 = A + (size_t)(m0 + row0 + 64) * K + gc * 8;
    const __bf16* Bg0 = Bt + (size_t)(n0 + row0) * K + gc * 8;
    const __bf16* Bg1 = Bt + (size_t)(n0 + row0 + 64) * K + gc * 8;
    const int wo512 = w * 512; // wave's element offset (rows 16w..16w+15)

#define STAGE(buf, k0)                                          \
    do {                                                        \
        gload16(Ag0 + (k0), &LDS_[buf][0][wo512]);              \
        gload16(Ag1 + (k0), &LDS_[buf][0][2048 + wo512]);       \
        gload16(Bg0 + (k0), &LDS_[buf][1][wo512]);              \
        gload16(Bg1 + (k0), &LDS_[buf][1][2048 + wo512]);       \
    } while (0)

    const int nk = K >> 5; // 32 K-steps
    STAGE(0, 0);
    STAGE(1, 32);
    int rb = 0, sb = 2;
    // lane-constant read-swizzle: slot = (l>>4) ^ ((l>>1)&3)  (rows are 16-aligned per frag)
    const int sc = (l >> 4) ^ ((l >> 1) & 3);
    for (int ki = 0; ki < nk; ++ki) {
        if (ki + 2 < nk) {
            STAGE(sb, (ki + 2) << 5);
            asm volatile("s_waitcnt vmcnt(8)" ::: "memory"); // tile ki done; ki+1,ki+2 in flight
        } else if (ki + 1 < nk) {
            asm volatile("s_waitcnt vmcnt(4)" ::: "memory");
        } else {
            asm volatile("s_waitcnt vmcnt(0)" ::: "memory");
        }
        __builtin_amdgcn_s_barrier();
        const char* rdA = (const char*)&LDS_[rb][0][0];
        const char* rdB = (const char*)&LDS_[rb][1][0];
        bf16x8 af[4], bf[4];
#pragma unroll
        for (int i = 0; i < 4; ++i)
            af[i] = *reinterpret_cast<const bf16x8*>(rdA + (wm + i * 16 + (l & 15)) * 64 + sc * 16);
#pragma unroll
        for (int j = 0; j < 4; ++j)
            bf[j] = *reinterpret_cast<const bf16x8*>(rdB + (wn + j * 16 + (l & 15)) * 64 + sc * 16);
#pragma unroll
        for (int i = 0; i < 4; ++i)
#pragma unroll
            for (int j = 0; j < 4; ++j)
                acc[i][j] = __builtin_amdgcn_mfma_f32_16x16x32_bf16(af[i], bf[j], acc[i][j], 0, 0, 0);
        __builtin_amdgcn_s_barrier();
        rb = (rb == 2) ? 0 : rb + 1;
        sb = (sb == 2) ? 0 : sb + 1;
    }
#undef STAGE

    if (EPI == 0) {
        const int cls = n0 >> 10; // 0=Q 1=K 2=V (N=3072, tile 128 never straddles)
        if (cls < 2) {
            const float* bias = (cls == 0) ? b0 : b1;
#pragma unroll
            for (int j = 0; j < 4; ++j) {
                const int e = n0 + wn + j * 16 + (l & 15);
                const int eh = e & 1023;
                const int h = eh >> 6, hd = eh & 63;
                const float bv = bias[eh];
#pragma unroll
                for (int i = 0; i < 4; ++i)
#pragma unroll
                    for (int r = 0; r < 4; ++r) {
                        const int m = m0 + wm + i * 16 + ((l >> 4) << 2) + r;
                        const int b = m >> 11, s = m & 2047;
                        float v = acc[i][j][r] + bv;
                        if (cls == 0) v *= SCALE_L2E; // fold softmax scale into Q
                        __bf16* dst = (cls == 0) ? Qo : Ko;
                        dst[((size_t)(b * 16 + h) * 2048 + s) * 64 + hd] = (__bf16)v;
                    }
            }
        } else {
            // V: transpose through LDS -> coalesced 16B stores along s, psi folded in.
            // LDS layout: row el (0..127 local e) x 256B (128 psi-positions), chunk-XOR swizzled.
            char* Tr = (char*)&LDS_[0][0][0]; // 32KB of the 48KB
#pragma unroll
            for (int j = 0; j < 4; ++j) {
                const int el = wn + j * 16 + (l & 15);
                const float bv = b2[(n0 & 1023) + el];
#pragma unroll
                for (int i = 0; i < 4; ++i) {
                    const int m4 = wm + i * 16 + ((l >> 4) << 2);
                    const int quad = (m4 >> 2) & 7;
                    const int pos0 = (m4 & 96) | ((quad & 3) << 3) | ((quad >> 2) << 2);
                    bf16x4 pkv = { (__bf16)(acc[i][j][0] + bv), (__bf16)(acc[i][j][1] + bv),
                                   (__bf16)(acc[i][j][2] + bv), (__bf16)(acc[i][j][3] + bv) };
                    const int byt = el * 256 + ((pos0 * 2) ^ ((el & 7) << 4));
                    *reinterpret_cast<bf16x4*>(Tr + byt) = pkv;
                }
            }
            __syncthreads();
            const int b = m0 >> 11, sblk = m0 & 2047;
#pragma unroll
            for (int rr = 0; rr < 8; ++rr) {
                const int er = w * 32 + rr * 4 + (l >> 4); // local e-row
                const int c = l & 15;                      // 16B chunk of the s-run
                const int slot = c ^ (er & 7);
                bf16x8 vv = *reinterpret_cast<const bf16x8*>(Tr + er * 256 + slot * 16);
                const int eg = (n0 & 1023) + er;
                const int h = eg >> 6, hd = eg & 63;
                char* dst = (char*)(Vo + ((size_t)(b * 16 + h) * 64 + hd) * 2048 + sblk) + c * 16;
                *reinterpret_cast<bf16x8*>(dst) = vv;
            }
        }
    } else {
#pragma unroll
        for (int j = 0; j < 4; ++j) {
            const int e = n0 + wn + j * 16 + (l & 15);
            const float bv = b0[e];
#pragma unroll
            for (int i = 0; i < 4; ++i)
#pragma unroll
                for (int r = 0; r < 4; ++r) {
                    const int m = m0 + wm + i * 16 + ((l >> 4) << 2) + r;
                    Fo[(size_t)m * 1024 + e] = acc[i][j][r] + bv;
                }
        }
    }
}

// Flash attention, causal, SWAPPED-operand form: S^T = mfma(K,Q), O^T = mfma(VT,P^T).
// Each lane owns ONE q row. P never touches LDS (V columns psi-permuted at producer).
// CAUSAL PAIRING: block x handles strips qt = 15-x (heavy, first) and qt = x (light):
// 34 tiles for EVERY block -> perfectly uniform 512-block grid, no straggler CUs.
__global__ __launch_bounds__(512) void attn_fwd(
    const __bf16* __restrict__ Qb, const __bf16* __restrict__ Kb,
    const __bf16* __restrict__ VTb, __bf16* __restrict__ Ob) {
    __shared__ __align__(16) __bf16 Ks[2][64 * 64];
    __shared__ __align__(16) __bf16 Vs[2][64 * 64];
    const int t = threadIdx.x, l = t & 63, w = t >> 6;
    const int bh = blockIdx.y;
    const int b = bh >> 4, h = bh & 15;

    const __bf16* Qg = Qb + (size_t)bh * S_ * 64;
    const __bf16* Kg = Kb + (size_t)bh * S_ * 64;
    const __bf16* Vg = VTb + (size_t)bh * 64 * S_;

    // staging: 512 16B chunks each for K and VT; dest linear, source pre-swizzled (involution)
    const int srow = t >> 3, sc = t & 7;
    const __bf16* Ksrc = Kg + (size_t)srow * 64 + ((sc ^ (srow & 7)) * 8);
    const __bf16* Vsrc = Vg + (size_t)srow * S_ + ((sc ^ (srow & 7)) * 8);
    __bf16* Kd0 = &Ks[0][(w * 64) * 8];
    __bf16* Kd1 = &Ks[1][(w * 64) * 8];
    __bf16* Vd0 = &Vs[0][(w * 64) * 8];
    __bf16* Vd1 = &Vs[1][(w * 64) * 8];

#pragma unroll 1
    for (int sidx = 0; sidx < 2; ++sidx) {
        const int qt = (sidx == 0) ? (15 - (int)blockIdx.x) : (int)blockIdx.x;
        const int qw = qt * 128 + w * 16;
        const int qg = qw + (l & 15); // this lane's q row

        bf16x8 qf[2];
        qf[0] = *reinterpret_cast<const bf16x8*>(Qg + (size_t)qg * 64 + (l >> 4) * 8);
        qf[1] = *reinterpret_cast<const bf16x8*>(Qg + (size_t)qg * 64 + 32 + (l >> 4) * 8);

        f32x4 o_acc[4] = {};
        float m_r = -INFINITY; // running max (log2 domain)
        float l_r = 0.f;       // running denom

        const int ktmax = 2 * qt + 1;
        gload16(Ksrc, Kd0);
        gload16(Vsrc, Vd0);
        int cur = 0;
        for (int kt = 0; kt <= ktmax; ++kt) {
            if (kt < ktmax) {
                gload16(Ksrc + (size_t)(kt + 1) * 4096, (cur == 0) ? Kd1 : Kd0);
                gload16(Vsrc + (kt + 1) * 64, (cur == 0) ? Vd1 : Vd0);
                asm volatile("s_waitcnt vmcnt(2)" ::: "memory"); // tile kt done, kt+1 in flight
            } else {
                asm volatile("s_waitcnt vmcnt(0)" ::: "memory");
            }
            __builtin_amdgcn_s_barrier();
            const char* kb = (cur == 0) ? (const char*)Ks[0] : (const char*)Ks[1];
            const char* vb = (cur == 0) ? (const char*)Vs[0] : (const char*)Vs[1];
            if (kt * 64 <= qw + 15) { // wave has at least one unmasked row
                // S^T = K Q^T : lane gets S[q = l&15][kv = j*16 + (l>>4)*4 + r]
                f32x4 sa[4] = {};
                __builtin_amdgcn_s_setprio(1);
#pragma unroll
                for (int kk = 0; kk < 2; ++kk) {
#pragma unroll
                    for (int j = 0; j < 4; ++j) {
                        const int row = j * 16 + (l & 15);
                        int byt = row * 128 + (kk * 32 + (l >> 4) * 8) * 2;
                        byt ^= (row & 7) << 4;
                        bf16x8 kf = *reinterpret_cast<const bf16x8*>(kb + byt);
                        sa[j] = __builtin_amdgcn_mfma_f32_16x16x32_bf16(kf, qf[kk], sa[j], 0, 0, 0);
                    }
                }
                __builtin_amdgcn_s_setprio(0);
                // causal mask (scale already folded into Q)
                float p[4][4];
                const bool bnd = (kt * 64 + 63) > qw; // only boundary tiles need masking
#pragma unroll
                for (int j = 0; j < 4; ++j) {
                    const int kv0 = kt * 64 + j * 16 + ((l >> 4) << 2);
#pragma unroll
                    for (int r = 0; r < 4; ++r) {
                        float x = sa[j][r];
                        if (bnd && (kv0 + r) > qg) x = -INFINITY;
                        p[j][r] = x;
                    }
                }
                // row max: in-register tree + 2 shuffles
                float mt;
                {
                    float a0 = fmaxf(fmaxf(p[0][0], p[0][1]), fmaxf(p[0][2], p[0][3]));
                    float a1 = fmaxf(fmaxf(p[1][0], p[1][1]), fmaxf(p[1][2], p[1][3]));
                    float a2 = fmaxf(fmaxf(p[2][0], p[2][1]), fmaxf(p[2][2], p[2][3]));
                    float a3 = fmaxf(fmaxf(p[3][0], p[3][1]), fmaxf(p[3][2], p[3][3]));
                    mt = fmaxf(fmaxf(a0, a1), fmaxf(a2, a3));
                    mt = fmaxf(mt, __shfl_xor(mt, 16));
                    mt = fmaxf(mt, __shfl_xor(mt, 32));
                }
                // defer-max (T13): skip rescale while growth <= 8 (values bounded by 2^8)
                if (!__all(mt - m_r <= 8.0f)) {
                    const float mn = fmaxf(m_r, mt);
                    const float al = exp2f(m_r - mn);
                    m_r = mn;
                    l_r *= al;
#pragma unroll
                    for (int j = 0; j < 4; ++j)
#pragma unroll
                        for (int r = 0; r < 4; ++r) o_acc[j][r] *= al;
                }
                float sum = 0.f;
#pragma unroll
                for (int j = 0; j < 4; ++j)
#pragma unroll
                    for (int r = 0; r < 4; ++r) {
                        const float e = exp2f(p[j][r] - m_r);
                        p[j][r] = e;
                        sum += e;
                    }
                sum += __shfl_xor(sum, 16);
                sum += __shfl_xor(sum, 32);
                l_r += sum;
                // O^T += VT P^T : P fragment is lane-local (V columns psi-permuted at producer)
                __builtin_amdgcn_s_setprio(1);
#pragma unroll
                for (int kk = 0; kk < 2; ++kk) {
                    u32x4 pwv = { pk2(p[2 * kk][0], p[2 * kk][1]), pk2(p[2 * kk][2], p[2 * kk][3]),
                                  pk2(p[2 * kk + 1][0], p[2 * kk + 1][1]), pk2(p[2 * kk + 1][2], p[2 * kk + 1][3]) };
                    bf16x8 pf = __builtin_bit_cast(bf16x8, pwv);
#pragma unroll
                    for (int j = 0; j < 4; ++j) {
                        const int hd = j * 16 + (l & 15);
                        int vb2 = hd * 128 + (kk * 32 + (l >> 4) * 8) * 2;
                        vb2 ^= (hd & 7) << 4;
                        bf16x8 vf = *reinterpret_cast<const bf16x8*>(vb + vb2);
                        o_acc[j] = __builtin_amdgcn_mfma_f32_16x16x32_bf16(vf, pf, o_acc[j], 0, 0, 0);
                    }
                }
                __builtin_amdgcn_s_setprio(0);
            }
            __builtin_amdgcn_s_barrier(); // all reads of buf[cur] done before it is re-staged
            cur ^= 1;
        }
        const float inv = 1.0f / l_r;
#pragma unroll
        for (int j = 0; j < 4; ++j) {
            bf16x4 ov = { (__bf16)(o_acc[j][0] * inv), (__bf16)(o_acc[j][1] * inv),
                          (__bf16)(o_acc[j][2] * inv), (__bf16)(o_acc[j][3] * inv) };
            const int hd = j * 16 + ((l >> 4) << 2);
            *reinterpret_cast<bf16x4*>(&Ob[(size_t)(b * 2048 + qg) * 1024 + h * 64 + hd]) = ov;
        }
    }
}

extern "C" void kernel_launch(void* const* d_in, const int* in_sizes, int n_in,
                              void* d_out, int out_size, void* d_ws, size_t ws_size,
                              hipStream_t stream) {
    const float* x  = (const float*)d_in[0];
    const float* wq = (const float*)d_in[2];
    const float* bq = (const float*)d_in[3];
    const float* wk = (const float*)d_in[4];
    const float* bk = (const float*)d_in[5];
    const float* wv = (const float*)d_in[6];
    const float* bv = (const float*)d_in[7];
    const float* wo = (const float*)d_in[8];
    const float* bo = (const float*)d_in[9];
    float* out = (float*)d_out;

    char* ws = (char*)d_ws;
    __bf16* xb   = (__bf16*)(ws);                 // 8192x1024        = 16,777,216 B
    __bf16* wqkv = (__bf16*)(ws + 16777216);      // 3072x1024        =  6,291,456 B
    __bf16* wob  = (__bf16*)(ws + 23068672);      // 1024x1024        =  2,097,152 B
    __bf16* Qb   = (__bf16*)(ws + 25165824);      // 64x2048x64       = 16,777,216 B
    __bf16* Kb   = (__bf16*)(ws + 41943040);      // 64x2048x64       = 16,777,216 B
    __bf16* VTb  = (__bf16*)(ws + 58720256);      // 64x64x2048       = 16,777,216 B
    __bf16* Ob   = (__bf16*)(ws + 75497472);      // 8192x1024        = 16,777,216 B

    cast_f32_bf16<<<8192, 256, 0, stream>>>(x, xb, 2097152);
    cast_f32_bf16<<<1024, 256, 0, stream>>>(wq, wqkv, 262144);
    cast_f32_bf16<<<1024, 256, 0, stream>>>(wk, wqkv + 1048576, 262144);
    cast_f32_bf16<<<1024, 256, 0, stream>>>(wv, wqkv + 2097152, 262144);
    cast_f32_bf16<<<1024, 256, 0, stream>>>(wo, wob, 262144);

    gemm_bt<0><<<dim3(24, 64), 256, 0, stream>>>(xb, wqkv, bq, bk, bv, Qb, Kb, VTb, nullptr, 1024);
    attn_fwd<<<dim3(8, 64), 512, 0, stream>>>(Qb, Kb, VTb, Ob);
    gemm_bt<1><<<dim3(8, 64), 256, 0, stream>>>(Ob, wob, bo, nullptr, nullptr, nullptr, nullptr, nullptr, out, 1024);
}

// Round 7
// 188.050 us; speedup vs baseline: 1.5373x; 1.0409x over previous
//
#include <hip/hip_runtime.h>
#include <hip/hip_bf16.h>
#include <math.h>

using bf16x8 = __attribute__((ext_vector_type(8))) __bf16;
using bf16x4 = __attribute__((ext_vector_type(4))) __bf16;
using f32x4  = __attribute__((ext_vector_type(4))) float;
using f32x16 = __attribute__((ext_vector_type(16))) float;
using u32x4  = __attribute__((ext_vector_type(4))) unsigned;

static constexpr int S_ = 2048;
static constexpr float SCALE_L2E = 0.125f * 1.44269504088896340736f; // 1/sqrt(64) * log2(e)

__device__ __forceinline__ void gload16(const void* g, void* lds) {
    __builtin_amdgcn_global_load_lds((const __attribute__((address_space(1))) void*)g,
                                     (__attribute__((address_space(3))) void*)lds, 16, 0, 0);
}

__device__ __forceinline__ unsigned pk2(float a, float b) {
    unsigned short lo = __builtin_bit_cast(unsigned short, (__bf16)a);
    unsigned short hi = __builtin_bit_cast(unsigned short, (__bf16)b);
    return (unsigned)lo | ((unsigned)hi << 16);
}

__global__ void cast_f32_bf16(const float* __restrict__ src, __bf16* __restrict__ dst, int n4) {
    int i = blockIdx.x * blockDim.x + threadIdx.x;
    if (i < n4) {
        float4 v = reinterpret_cast<const float4*>(src)[i];
        bf16x4 o = { (__bf16)v.x, (__bf16)v.y, (__bf16)v.z, (__bf16)v.w };
        reinterpret_cast<bf16x4*>(dst)[i] = o;
    }
}

// C[m,n] = sum_k A[m,k] * Bt[n,k]   (A: MxK row-major bf16, Bt: NxK row-major bf16)
// 128x128 tile, BK=32, 3-deep LDS pipeline with counted vmcnt, chunk-XOR LDS swizzle.
// EPI 0: QKV epilogue. Q pre-scaled by 1/sqrt(d)*log2e, K row-major per head;
//        V transposed per head WITH psi' kv-permutation (32x32 PV lane-local layout),
//        written COALESCED via an LDS transpose.
// EPI 1: fp32 output epilogue + bias
template <int EPI>
__global__ __launch_bounds__(256) void gemm_bt(
    const __bf16* __restrict__ A, const __bf16* __restrict__ Bt,
    const float* __restrict__ b0, const float* __restrict__ b1, const float* __restrict__ b2,
    __bf16* __restrict__ Qo, __bf16* __restrict__ Ko, __bf16* __restrict__ Vo,
    float* __restrict__ Fo, int K) {
    __shared__ __align__(16) __bf16 LDS_[3][2][4096]; // [buf][A/B][128 rows x 32 cols], 48KB
    const int t = threadIdx.x, l = t & 63, w = t >> 6;
    const int m0 = blockIdx.y * 128, n0 = blockIdx.x * 128;
    const int wm = (w >> 1) * 64, wn = (w & 1) * 64;
    f32x4 acc[4][4] = {};

    const int row0 = t >> 2, cw0 = t & 3;
    const int gc = cw0 ^ ((row0 >> 1) & 3);
    const __bf16* Ag0 = A + (size_t)(m0 + row0) * K + gc * 8;
    const __bf16* Ag1 = A + (size_t)(m0 + row0 + 64) * K + gc * 8;
    const __bf16* Bg0 = Bt + (size_t)(n0 + row0) * K + gc * 8;
    const __bf16* Bg1 = Bt + (size_t)(n0 + row0 + 64) * K + gc * 8;
    const int wo512 = w * 512;

#define STAGE(buf, k0)                                          \
    do {                                                        \
        gload16(Ag0 + (k0), &LDS_[buf][0][wo512]);              \
        gload16(Ag1 + (k0), &LDS_[buf][0][2048 + wo512]);       \
        gload16(Bg0 + (k0), &LDS_[buf][1][wo512]);              \
        gload16(Bg1 + (k0), &LDS_[buf][1][2048 + wo512]);       \
    } while (0)

    const int nk = K >> 5;
    STAGE(0, 0);
    STAGE(1, 32);
    int rb = 0, sb = 2;
    const int sc = (l >> 4) ^ ((l >> 1) & 3);
    for (int ki = 0; ki < nk; ++ki) {
        if (ki + 2 < nk) {
            STAGE(sb, (ki + 2) << 5);
            asm volatile("s_waitcnt vmcnt(8)" ::: "memory");
        } else if (ki + 1 < nk) {
            asm volatile("s_waitcnt vmcnt(4)" ::: "memory");
        } else {
            asm volatile("s_waitcnt vmcnt(0)" ::: "memory");
        }
        __builtin_amdgcn_s_barrier();
        const char* rdA = (const char*)&LDS_[rb][0][0];
        const char* rdB = (const char*)&LDS_[rb][1][0];
        bf16x8 af[4], bf[4];
#pragma unroll
        for (int i = 0; i < 4; ++i)
            af[i] = *reinterpret_cast<const bf16x8*>(rdA + (wm + i * 16 + (l & 15)) * 64 + sc * 16);
#pragma unroll
        for (int j = 0; j < 4; ++j)
            bf[j] = *reinterpret_cast<const bf16x8*>(rdB + (wn + j * 16 + (l & 15)) * 64 + sc * 16);
#pragma unroll
        for (int i = 0; i < 4; ++i)
#pragma unroll
            for (int j = 0; j < 4; ++j)
                acc[i][j] = __builtin_amdgcn_mfma_f32_16x16x32_bf16(af[i], bf[j], acc[i][j], 0, 0, 0);
        __builtin_amdgcn_s_barrier();
        rb = (rb == 2) ? 0 : rb + 1;
        sb = (sb == 2) ? 0 : sb + 1;
    }
#undef STAGE

    if (EPI == 0) {
        const int cls = n0 >> 10; // 0=Q 1=K 2=V
        if (cls < 2) {
            const float* bias = (cls == 0) ? b0 : b1;
#pragma unroll
            for (int j = 0; j < 4; ++j) {
                const int e = n0 + wn + j * 16 + (l & 15);
                const int eh = e & 1023;
                const int h = eh >> 6, hd = eh & 63;
                const float bv = bias[eh];
#pragma unroll
                for (int i = 0; i < 4; ++i)
#pragma unroll
                    for (int r = 0; r < 4; ++r) {
                        const int m = m0 + wm + i * 16 + ((l >> 4) << 2) + r;
                        const int b = m >> 11, s = m & 2047;
                        float v = acc[i][j][r] + bv;
                        if (cls == 0) v *= SCALE_L2E;
                        __bf16* dst = (cls == 0) ? Qo : Ko;
                        dst[((size_t)(b * 16 + h) * 2048 + s) * 64 + hd] = (__bf16)v;
                    }
            }
        } else {
            // V: transpose through LDS -> coalesced 16B stores along s, psi' folded in.
            // psi' (32x32 PV layout): pos = (kv&112) | ((kv&4)<<1) | ((kv&8)>>1) | (kv&3)
            char* Tr = (char*)&LDS_[0][0][0];
#pragma unroll
            for (int j = 0; j < 4; ++j) {
                const int el = wn + j * 16 + (l & 15);
                const float bv = b2[(n0 & 1023) + el];
#pragma unroll
                for (int i = 0; i < 4; ++i) {
                    const int m4 = wm + i * 16 + ((l >> 4) << 2); // 4-aligned kv base
                    const int pos0 = (m4 & 112) | ((m4 & 4) << 1) | ((m4 & 8) >> 1);
                    bf16x4 pkv = { (__bf16)(acc[i][j][0] + bv), (__bf16)(acc[i][j][1] + bv),
                                   (__bf16)(acc[i][j][2] + bv), (__bf16)(acc[i][j][3] + bv) };
                    const int byt = el * 256 + ((pos0 * 2) ^ ((el & 7) << 4));
                    *reinterpret_cast<bf16x4*>(Tr + byt) = pkv;
                }
            }
            __syncthreads();
            const int b = m0 >> 11, sblk = m0 & 2047;
#pragma unroll
            for (int rr = 0; rr < 8; ++rr) {
                const int er = w * 32 + rr * 4 + (l >> 4);
                const int c = l & 15;
                const int slot = c ^ (er & 7);
                bf16x8 vv = *reinterpret_cast<const bf16x8*>(Tr + er * 256 + slot * 16);
                const int eg = (n0 & 1023) + er;
                const int h = eg >> 6, hd = eg & 63;
                char* dst = (char*)(Vo + ((size_t)(b * 16 + h) * 64 + hd) * 2048 + sblk) + c * 16;
                *reinterpret_cast<bf16x8*>(dst) = vv;
            }
        }
    } else {
#pragma unroll
        for (int j = 0; j < 4; ++j) {
            const int e = n0 + wn + j * 16 + (l & 15);
            const float bv = b0[e];
#pragma unroll
            for (int i = 0; i < 4; ++i)
#pragma unroll
                for (int r = 0; r < 4; ++r) {
                    const int m = m0 + wm + i * 16 + ((l >> 4) << 2) + r;
                    Fo[(size_t)m * 1024 + e] = acc[i][j][r] + bv;
                }
        }
    }
}

// Flash attention, causal. 32x32x16 MFMA, swapped operands: S^T = mfma(K,Q), O^T = mfma(VT,P).
// Each lane owns ONE q row (q = qs + (l&31)); 32 kv scores/lane/tile across 2 MFMA halves;
// softmax reduce = in-register tree + one shfl_xor(32). PV B-frag is lane-local via psi'
// (V kv-permuted at producer): QK output regs [8(m&1)..+8) of half m>>1 ARE chunk m's B-frag.
// Blocks: 4 waves x 32q = 128 rows, causal-paired (34 tiles each, uniform), 512 blocks.
// XCD clustering: bh = (id&7)*8 + ((id>>3)&7) -> same-bh blocks share one XCD's L2.
__global__ __launch_bounds__(256, 2) void attn_fwd(
    const __bf16* __restrict__ Qb, const __bf16* __restrict__ Kb,
    const __bf16* __restrict__ VTb, __bf16* __restrict__ Ob) {
    __shared__ __align__(16) __bf16 Ks[2][64 * 64];
    __shared__ __align__(16) __bf16 Vs[2][64 * 64];
    const int t = threadIdx.x, l = t & 63, w = t >> 6;
    const int id = blockIdx.x;
    const int bh = (id & 7) * 8 + ((id >> 3) & 7); // XCD-clustered
    const int xp = id >> 6;                        // pair index 0..7
    const int b = bh >> 4, hh = bh & 15;
    const int hl = l >> 5, l31 = l & 31;

    const __bf16* Qg = Qb + (size_t)bh * S_ * 64;
    const __bf16* Kg = Kb + (size_t)bh * S_ * 64;
    const __bf16* Vg = VTb + (size_t)bh * 64 * S_;

    // staging: wave w covers rows 16w..16w+15, 2 passes of 8 rows; lane l -> row +(l>>3),
    // 16B slot (l&7); source chunk pre-swizzled by ^(row&7) = ^(l>>3) (involution)
    const int l3 = l >> 3, gc8 = ((l & 7) ^ l3) * 8;
    const __bf16* Ksrc0 = Kg + (size_t)(16 * w + l3) * 64 + gc8;
    const __bf16* Ksrc1 = Kg + (size_t)(16 * w + 8 + l3) * 64 + gc8;
    const __bf16* Vsrc0 = Vg + (size_t)(16 * w + l3) * S_ + gc8;
    const __bf16* Vsrc1 = Vg + (size_t)(16 * w + 8 + l3) * S_ + gc8;
    __bf16* K0a = &Ks[0][w * 1024]; __bf16* K0b = K0a + 512;
    __bf16* K1a = &Ks[1][w * 1024]; __bf16* K1b = K1a + 512;
    __bf16* V0a = &Vs[0][w * 1024]; __bf16* V0b = V0a + 512;
    __bf16* V1a = &Vs[1][w * 1024]; __bf16* V1b = V1a + 512;

#pragma unroll 1
    for (int sidx = 0; sidx < 2; ++sidx) {
        const int qt = (sidx == 0) ? (15 - xp) : xp; // heavy strip first (L2-warms light strip)
        const int qs = qt * 128 + w * 32;
        const int qg = qs + l31;

        bf16x8 qf[4];
#pragma unroll
        for (int c = 0; c < 4; ++c)
            qf[c] = *reinterpret_cast<const bf16x8*>(Qg + (size_t)qg * 64 + c * 16 + hl * 8);

        f32x16 o0 = {}, o1 = {};
        float m_r = -INFINITY, l_r = 0.f;

        const int ktmax = 2 * qt + 1;
        gload16(Ksrc0, K0a); gload16(Ksrc1, K0b);
        gload16(Vsrc0, V0a); gload16(Vsrc1, V0b);
        int cur = 0;
        for (int kt = 0; kt <= ktmax; ++kt) {
            if (kt < ktmax) {
                const size_t ko = (size_t)(kt + 1) * 4096;
                const int ho = (kt + 1) * 64;
                gload16(Ksrc0 + ko, (cur == 0) ? K1a : K0a);
                gload16(Ksrc1 + ko, (cur == 0) ? K1b : K0b);
                gload16(Vsrc0 + ho, (cur == 0) ? V1a : V0a);
                gload16(Vsrc1 + ho, (cur == 0) ? V1b : V0b);
                asm volatile("s_waitcnt vmcnt(4)" ::: "memory"); // tile kt done, kt+1 in flight
            } else {
                asm volatile("s_waitcnt vmcnt(0)" ::: "memory");
            }
            __builtin_amdgcn_s_barrier();
            const char* kb = (cur == 0) ? (const char*)Ks[0] : (const char*)Ks[1];
            const char* vb = (cur == 0) ? (const char*)Vs[0] : (const char*)Vs[1];
            if (kt * 64 <= qs + 31) {
                const int xs = (l & 7) << 4; // row&7 == l&7 for all frag rows used below
                // S^T halves: s0 = kv 0..31, s1 = kv 32..63 (rows (r&3)+8(r>>2)+4hl)
                f32x16 s0 = {}, s1 = {};
                __builtin_amdgcn_s_setprio(1);
#pragma unroll
                for (int c = 0; c < 4; ++c) {
                    bf16x8 kf0 = *reinterpret_cast<const bf16x8*>(kb + l31 * 128 + ((c * 32 + hl * 16) ^ xs));
                    s0 = __builtin_amdgcn_mfma_f32_32x32x16_bf16(kf0, qf[c], s0, 0, 0, 0);
                }
#pragma unroll
                for (int c = 0; c < 4; ++c) {
                    bf16x8 kf1 = *reinterpret_cast<const bf16x8*>(kb + (32 + l31) * 128 + ((c * 32 + hl * 16) ^ xs));
                    s1 = __builtin_amdgcn_mfma_f32_32x32x16_bf16(kf1, qf[c], s1, 0, 0, 0);
                }
                __builtin_amdgcn_s_setprio(0);
                float p0[16], p1[16];
                const int ktb = kt * 64;
                const bool bnd = (ktb + 63) > qs;
                if (bnd) {
#pragma unroll
                    for (int r = 0; r < 16; ++r) {
                        const int kvr = ktb + (r & 3) + 8 * (r >> 2) + 4 * hl;
                        p0[r] = (kvr > qg) ? -INFINITY : s0[r];
                        p1[r] = (kvr + 32 > qg) ? -INFINITY : s1[r];
                    }
                } else {
#pragma unroll
                    for (int r = 0; r < 16; ++r) { p0[r] = s0[r]; p1[r] = s1[r]; }
                }
                // row max: 31-op tree + 1 shfl (lane l^32 holds complementary kv of same q)
                float mx[16];
#pragma unroll
                for (int r = 0; r < 16; ++r) mx[r] = fmaxf(p0[r], p1[r]);
#pragma unroll
                for (int s2 = 8; s2 > 0; s2 >>= 1)
#pragma unroll
                    for (int r = 0; r < 8; ++r) if (r < s2) mx[r] = fmaxf(mx[r], mx[r + s2]);
                float mt = fmaxf(mx[0], __shfl_xor(mx[0], 32));
                // defer-max (T13)
                if (!__all(mt - m_r <= 8.0f)) {
                    const float mn = fmaxf(m_r, mt);
                    const float al = exp2f(m_r - mn);
                    m_r = mn;
                    l_r *= al;
#pragma unroll
                    for (int r = 0; r < 16; ++r) { o0[r] *= al; o1[r] *= al; }
                }
                float sm[16];
#pragma unroll
                for (int r = 0; r < 16; ++r) {
                    p0[r] = exp2f(p0[r] - m_r);
                    p1[r] = exp2f(p1[r] - m_r);
                    sm[r] = p0[r] + p1[r];
                }
#pragma unroll
                for (int s2 = 8; s2 > 0; s2 >>= 1)
#pragma unroll
                    for (int r = 0; r < 8; ++r) if (r < s2) sm[r] += sm[r + s2];
                l_r += sm[0] + __shfl_xor(sm[0], 32);
                // pack P: chunk m B-frag = own regs [8(m&1)..+8) of half m>>1
                u32x4 w0 = { pk2(p0[0], p0[1]), pk2(p0[2], p0[3]), pk2(p0[4], p0[5]), pk2(p0[6], p0[7]) };
                u32x4 w1 = { pk2(p0[8], p0[9]), pk2(p0[10], p0[11]), pk2(p0[12], p0[13]), pk2(p0[14], p0[15]) };
                u32x4 w2 = { pk2(p1[0], p1[1]), pk2(p1[2], p1[3]), pk2(p1[4], p1[5]), pk2(p1[6], p1[7]) };
                u32x4 w3 = { pk2(p1[8], p1[9]), pk2(p1[10], p1[11]), pk2(p1[12], p1[13]), pk2(p1[14], p1[15]) };
                bf16x8 pf0 = __builtin_bit_cast(bf16x8, w0);
                bf16x8 pf1 = __builtin_bit_cast(bf16x8, w1);
                bf16x8 pf2 = __builtin_bit_cast(bf16x8, w2);
                bf16x8 pf3 = __builtin_bit_cast(bf16x8, w3);
                // O^T += VT_psi' P : A-frag rows = hd, k-slots = permuted kv positions
                __builtin_amdgcn_s_setprio(1);
#pragma unroll
                for (int a = 0; a < 2; ++a) {
                    const int rb2 = (a * 32 + l31) * 128;
                    bf16x8 vf0 = *reinterpret_cast<const bf16x8*>(vb + rb2 + ((0 * 32 + hl * 16) ^ xs));
                    bf16x8 vf1 = *reinterpret_cast<const bf16x8*>(vb + rb2 + ((1 * 32 + hl * 16) ^ xs));
                    bf16x8 vf2 = *reinterpret_cast<const bf16x8*>(vb + rb2 + ((2 * 32 + hl * 16) ^ xs));
                    bf16x8 vf3 = *reinterpret_cast<const bf16x8*>(vb + rb2 + ((3 * 32 + hl * 16) ^ xs));
                    if (a == 0) {
                        o0 = __builtin_amdgcn_mfma_f32_32x32x16_bf16(vf0, pf0, o0, 0, 0, 0);
                        o0 = __builtin_amdgcn_mfma_f32_32x32x16_bf16(vf1, pf1, o0, 0, 0, 0);
                        o0 = __builtin_amdgcn_mfma_f32_32x32x16_bf16(vf2, pf2, o0, 0, 0, 0);
                        o0 = __builtin_amdgcn_mfma_f32_32x32x16_bf16(vf3, pf3, o0, 0, 0, 0);
                    } else {
                        o1 = __builtin_amdgcn_mfma_f32_32x32x16_bf16(vf0, pf0, o1, 0, 0, 0);
                        o1 = __builtin_amdgcn_mfma_f32_32x32x16_bf16(vf1, pf1, o1, 0, 0, 0);
                        o1 = __builtin_amdgcn_mfma_f32_32x32x16_bf16(vf2, pf2, o1, 0, 0, 0);
                        o1 = __builtin_amdgcn_mfma_f32_32x32x16_bf16(vf3, pf3, o1, 0, 0, 0);
                    }
                }
                __builtin_amdgcn_s_setprio(0);
            }
            __builtin_amdgcn_s_barrier();
            cur ^= 1;
        }
        const float inv = 1.0f / l_r;
        __bf16* ob = Ob + (size_t)(b * 2048 + qg) * 1024 + hh * 64;
#pragma unroll
        for (int g = 0; g < 4; ++g) {
            bf16x4 v0 = { (__bf16)(o0[4 * g + 0] * inv), (__bf16)(o0[4 * g + 1] * inv),
                          (__bf16)(o0[4 * g + 2] * inv), (__bf16)(o0[4 * g + 3] * inv) };
            bf16x4 v1 = { (__bf16)(o1[4 * g + 0] * inv), (__bf16)(o1[4 * g + 1] * inv),
                          (__bf16)(o1[4 * g + 2] * inv), (__bf16)(o1[4 * g + 3] * inv) };
            *reinterpret_cast<bf16x4*>(ob + 8 * g + 4 * hl) = v0;
            *reinterpret_cast<bf16x4*>(ob + 32 + 8 * g + 4 * hl) = v1;
        }
    }
}

extern "C" void kernel_launch(void* const* d_in, const int* in_sizes, int n_in,
                              void* d_out, int out_size, void* d_ws, size_t ws_size,
                              hipStream_t stream) {
    const float* x  = (const float*)d_in[0];
    const float* wq = (const float*)d_in[2];
    const float* bq = (const float*)d_in[3];
    const float* wk = (const float*)d_in[4];
    const float* bk = (const float*)d_in[5];
    const float* wv = (const float*)d_in[6];
    const float* bv = (const float*)d_in[7];
    const float* wo = (const float*)d_in[8];
    const float* bo = (const float*)d_in[9];
    float* out = (float*)d_out;

    char* ws = (char*)d_ws;
    __bf16* xb   = (__bf16*)(ws);                 // 8192x1024
    __bf16* wqkv = (__bf16*)(ws + 16777216);      // 3072x1024
    __bf16* wob  = (__bf16*)(ws + 23068672);      // 1024x1024
    __bf16* Qb   = (__bf16*)(ws + 25165824);      // 64x2048x64
    __bf16* Kb   = (__bf16*)(ws + 41943040);      // 64x2048x64
    __bf16* VTb  = (__bf16*)(ws + 58720256);      // 64x64x2048 (psi'-permuted)
    __bf16* Ob   = (__bf16*)(ws + 75497472);      // 8192x1024

    cast_f32_bf16<<<8192, 256, 0, stream>>>(x, xb, 2097152);
    cast_f32_bf16<<<1024, 256, 0, stream>>>(wq, wqkv, 262144);
    cast_f32_bf16<<<1024, 256, 0, stream>>>(wk, wqkv + 1048576, 262144);
    cast_f32_bf16<<<1024, 256, 0, stream>>>(wv, wqkv + 2097152, 262144);
    cast_f32_bf16<<<1024, 256, 0, stream>>>(wo, wob, 262144);

    gemm_bt<0><<<dim3(24, 64), 256, 0, stream>>>(xb, wqkv, bq, bk, bv, Qb, Kb, VTb, nullptr, 1024);
    attn_fwd<<<512, 256, 0, stream>>>(Qb, Kb, VTb, Ob);
    gemm_bt<1><<<dim3(8, 64), 256, 0, stream>>>(Ob, wob, bo, nullptr, nullptr, nullptr, nullptr, nullptr, out, 1024);
}

// Round 8
// 185.017 us; speedup vs baseline: 1.5625x; 1.0164x over previous
//
#include <hip/hip_runtime.h>
#include <hip/hip_bf16.h>
#include <math.h>

using bf16x8 = __attribute__((ext_vector_type(8))) __bf16;
using bf16x4 = __attribute__((ext_vector_type(4))) __bf16;
using f32x4  = __attribute__((ext_vector_type(4))) float;
using f32x16 = __attribute__((ext_vector_type(16))) float;
using u32x4  = __attribute__((ext_vector_type(4))) unsigned;

static constexpr int S_ = 2048;
static constexpr float SCALE_L2E = 0.125f * 1.44269504088896340736f; // 1/sqrt(64) * log2(e)

__device__ __forceinline__ void gload16(const void* g, void* lds) {
    __builtin_amdgcn_global_load_lds((const __attribute__((address_space(1))) void*)g,
                                     (__attribute__((address_space(3))) void*)lds, 16, 0, 0);
}

__device__ __forceinline__ unsigned pk2(float a, float b) {
    unsigned short lo = __builtin_bit_cast(unsigned short, (__bf16)a);
    unsigned short hi = __builtin_bit_cast(unsigned short, (__bf16)b);
    return (unsigned)lo | ((unsigned)hi << 16);
}

__device__ __forceinline__ float max3f(float a, float b, float c) {
    return fmaxf(fmaxf(a, b), c); // clang fuses to v_max3_f32
}

__global__ void cast_f32_bf16(const float* __restrict__ src, __bf16* __restrict__ dst, int n4) {
    int i = blockIdx.x * blockDim.x + threadIdx.x;
    if (i < n4) {
        float4 v = reinterpret_cast<const float4*>(src)[i];
        bf16x4 o = { (__bf16)v.x, (__bf16)v.y, (__bf16)v.z, (__bf16)v.w };
        reinterpret_cast<bf16x4*>(dst)[i] = o;
    }
}

// C[m,n] = sum_k A[m,k] * Bt[n,k]   (A: MxK row-major bf16, Bt: NxK row-major bf16)
// 128x128 tile, BK=32, 3-deep LDS pipeline with counted vmcnt, chunk-XOR LDS swizzle.
// EPI 0: QKV epilogue. Q pre-scaled by 1/sqrt(d)*log2e, K row-major per head;
//        V transposed per head WITH psi' kv-permutation (32x32 PV lane-local layout),
//        written COALESCED via an LDS transpose.
// EPI 1: fp32 output epilogue + bias
template <int EPI>
__global__ __launch_bounds__(256) void gemm_bt(
    const __bf16* __restrict__ A, const __bf16* __restrict__ Bt,
    const float* __restrict__ b0, const float* __restrict__ b1, const float* __restrict__ b2,
    __bf16* __restrict__ Qo, __bf16* __restrict__ Ko, __bf16* __restrict__ Vo,
    float* __restrict__ Fo, int K) {
    __shared__ __align__(16) __bf16 LDS_[3][2][4096]; // [buf][A/B][128 rows x 32 cols], 48KB
    const int t = threadIdx.x, l = t & 63, w = t >> 6;
    const int m0 = blockIdx.y * 128, n0 = blockIdx.x * 128;
    const int wm = (w >> 1) * 64, wn = (w & 1) * 64;
    f32x4 acc[4][4] = {};

    const int row0 = t >> 2, cw0 = t & 3;
    const int gc = cw0 ^ ((row0 >> 1) & 3);
    const __bf16* Ag0 = A + (size_t)(m0 + row0) * K + gc * 8;
    const __bf16* Ag1 = A + (size_t)(m0 + row0 + 64) * K + gc * 8;
    const __bf16* Bg0 = Bt + (size_t)(n0 + row0) * K + gc * 8;
    const __bf16* Bg1 = Bt + (size_t)(n0 + row0 + 64) * K + gc * 8;
    const int wo512 = w * 512;

#define STAGE(buf, k0)                                          \
    do {                                                        \
        gload16(Ag0 + (k0), &LDS_[buf][0][wo512]);              \
        gload16(Ag1 + (k0), &LDS_[buf][0][2048 + wo512]);       \
        gload16(Bg0 + (k0), &LDS_[buf][1][wo512]);              \
        gload16(Bg1 + (k0), &LDS_[buf][1][2048 + wo512]);       \
    } while (0)

    const int nk = K >> 5;
    STAGE(0, 0);
    STAGE(1, 32);
    int rb = 0, sb = 2;
    const int sc = (l >> 4) ^ ((l >> 1) & 3);
    for (int ki = 0; ki < nk; ++ki) {
        if (ki + 2 < nk) {
            STAGE(sb, (ki + 2) << 5);
            asm volatile("s_waitcnt vmcnt(8)" ::: "memory");
        } else if (ki + 1 < nk) {
            asm volatile("s_waitcnt vmcnt(4)" ::: "memory");
        } else {
            asm volatile("s_waitcnt vmcnt(0)" ::: "memory");
        }
        __builtin_amdgcn_s_barrier();
        const char* rdA = (const char*)&LDS_[rb][0][0];
        const char* rdB = (const char*)&LDS_[rb][1][0];
        bf16x8 af[4], bf[4];
#pragma unroll
        for (int i = 0; i < 4; ++i)
            af[i] = *reinterpret_cast<const bf16x8*>(rdA + (wm + i * 16 + (l & 15)) * 64 + sc * 16);
#pragma unroll
        for (int j = 0; j < 4; ++j)
            bf[j] = *reinterpret_cast<const bf16x8*>(rdB + (wn + j * 16 + (l & 15)) * 64 + sc * 16);
#pragma unroll
        for (int i = 0; i < 4; ++i)
#pragma unroll
            for (int j = 0; j < 4; ++j)
                acc[i][j] = __builtin_amdgcn_mfma_f32_16x16x32_bf16(af[i], bf[j], acc[i][j], 0, 0, 0);
        __builtin_amdgcn_s_barrier();
        rb = (rb == 2) ? 0 : rb + 1;
        sb = (sb == 2) ? 0 : sb + 1;
    }
#undef STAGE

    if (EPI == 0) {
        const int cls = n0 >> 10; // 0=Q 1=K 2=V
        if (cls < 2) {
            const float* bias = (cls == 0) ? b0 : b1;
#pragma unroll
            for (int j = 0; j < 4; ++j) {
                const int e = n0 + wn + j * 16 + (l & 15);
                const int eh = e & 1023;
                const int h = eh >> 6, hd = eh & 63;
                const float bv = bias[eh];
#pragma unroll
                for (int i = 0; i < 4; ++i)
#pragma unroll
                    for (int r = 0; r < 4; ++r) {
                        const int m = m0 + wm + i * 16 + ((l >> 4) << 2) + r;
                        const int b = m >> 11, s = m & 2047;
                        float v = acc[i][j][r] + bv;
                        if (cls == 0) v *= SCALE_L2E;
                        __bf16* dst = (cls == 0) ? Qo : Ko;
                        dst[((size_t)(b * 16 + h) * 2048 + s) * 64 + hd] = (__bf16)v;
                    }
            }
        } else {
            // V: transpose through LDS -> coalesced 16B stores along s, psi' folded in.
            // psi' (32x32 PV layout): pos = (kv&112) | ((kv&4)<<1) | ((kv&8)>>1) | (kv&3)
            char* Tr = (char*)&LDS_[0][0][0];
#pragma unroll
            for (int j = 0; j < 4; ++j) {
                const int el = wn + j * 16 + (l & 15);
                const float bv = b2[(n0 & 1023) + el];
#pragma unroll
                for (int i = 0; i < 4; ++i) {
                    const int m4 = wm + i * 16 + ((l >> 4) << 2); // 4-aligned kv base
                    const int pos0 = (m4 & 112) | ((m4 & 4) << 1) | ((m4 & 8) >> 1);
                    bf16x4 pkv = { (__bf16)(acc[i][j][0] + bv), (__bf16)(acc[i][j][1] + bv),
                                   (__bf16)(acc[i][j][2] + bv), (__bf16)(acc[i][j][3] + bv) };
                    const int byt = el * 256 + ((pos0 * 2) ^ ((el & 7) << 4));
                    *reinterpret_cast<bf16x4*>(Tr + byt) = pkv;
                }
            }
            __syncthreads();
            const int b = m0 >> 11, sblk = m0 & 2047;
#pragma unroll
            for (int rr = 0; rr < 8; ++rr) {
                const int er = w * 32 + rr * 4 + (l >> 4);
                const int c = l & 15;
                const int slot = c ^ (er & 7);
                bf16x8 vv = *reinterpret_cast<const bf16x8*>(Tr + er * 256 + slot * 16);
                const int eg = (n0 & 1023) + er;
                const int h = eg >> 6, hd = eg & 63;
                char* dst = (char*)(Vo + ((size_t)(b * 16 + h) * 64 + hd) * 2048 + sblk) + c * 16;
                *reinterpret_cast<bf16x8*>(dst) = vv;
            }
        }
    } else {
#pragma unroll
        for (int j = 0; j < 4; ++j) {
            const int e = n0 + wn + j * 16 + (l & 15);
            const float bv = b0[e];
#pragma unroll
            for (int i = 0; i < 4; ++i)
#pragma unroll
                for (int r = 0; r < 4; ++r) {
                    const int m = m0 + wm + i * 16 + ((l >> 4) << 2) + r;
                    Fo[(size_t)m * 1024 + e] = acc[i][j][r] + bv;
                }
        }
    }
}

// Flash attention, causal. 32x32x16 MFMA, swapped operands: S^T = mfma(K,Q), O^T = mfma(VT,P).
// Each lane owns ONE q row (q = qs + (l&31)); PV B-frag is lane-local via psi' (V kv-permuted
// at producer): QK output regs [8(m&1)..+8) of half m>>1 ARE chunk m's B-frag.
// COMBINED-PAIR blocks: 8 waves (512 thr); waves 0-3 = heavy strip (qt=15-xp), waves 4-7 =
// light strip (qt=xp); both share one K/V staging (1 K + 1 V gload per wave per tile).
// Light waves fail the compute guard on late tiles and barrier-spin (cheap).
// Per-CU balance: xp = g<4 ? g : 11-g -> the CU's two blocks sum to 50 iters, all CUs equal.
// XCD clustering: bh = (id&7)*8 + ((id>>3)&7) -> same-bh blocks share one XCD's L2.
__global__ __launch_bounds__(512, 4) void attn_fwd(
    const __bf16* __restrict__ Qb, const __bf16* __restrict__ Kb,
    const __bf16* __restrict__ VTb, __bf16* __restrict__ Ob) {
    __shared__ __align__(16) __bf16 Ks[2][64 * 64];
    __shared__ __align__(16) __bf16 Vs[2][64 * 64];
    const int t = threadIdx.x, l = t & 63, w = t >> 6; // w 0..7
    const int id = blockIdx.x;
    const int bh = (id & 7) * 8 + ((id >> 3) & 7); // XCD-clustered
    const int g = id >> 6;                          // 0..7
    const int xp = (g < 4) ? g : 11 - g;            // pair index, CU-balanced
    const int b = bh >> 4, hh = bh & 15;
    const int hl = l >> 5, l31 = l & 31;

    const __bf16* Qg = Qb + (size_t)bh * S_ * 64;
    const __bf16* Kg = Kb + (size_t)bh * S_ * 64;
    const __bf16* Vg = VTb + (size_t)bh * 64 * S_;

    // strip assignment: waves 0-3 heavy (long chain), 4-7 light
    const int qt = (w >> 2) ? xp : (15 - xp);
    const int sw = w & 3;
    const int qs = qt * 128 + sw * 32;
    const int qg = qs + l31;

    // staging: wave w stages K rows 8w..8w+7 and V rows 8w..8w+7 (1 gload16 each).
    // lane l -> row 8w+(l>>3), 16B slot (l&7); source chunk pre-swizzled by ^(row&7)=(l>>3)
    const int l3 = l >> 3, gc8 = ((l & 7) ^ l3) * 8;
    const __bf16* Ksrc = Kg + (size_t)(8 * w + l3) * 64 + gc8;
    const __bf16* Vsrc = Vg + (size_t)(8 * w + l3) * S_ + gc8;
    __bf16* Kd0 = &Ks[0][w * 512]; __bf16* Kd1 = &Ks[1][w * 512];
    __bf16* Vd0 = &Vs[0][w * 512]; __bf16* Vd1 = &Vs[1][w * 512];

    bf16x8 qf[4];
#pragma unroll
    for (int c = 0; c < 4; ++c)
        qf[c] = *reinterpret_cast<const bf16x8*>(Qg + (size_t)qg * 64 + c * 16 + hl * 8);

    f32x16 o0 = {}, o1 = {};
    float m_r = -INFINITY, l_r = 0.f;

    const int ktmax_blk = 2 * (15 - xp) + 1; // heavy strip's range governs the loop
    gload16(Ksrc, Kd0);
    gload16(Vsrc, Vd0);
    int cur = 0;
    for (int kt = 0; kt <= ktmax_blk; ++kt) {
        if (kt < ktmax_blk) {
            const size_t ko = (size_t)(kt + 1) * 4096;
            gload16(Ksrc + ko, (cur == 0) ? Kd1 : Kd0);
            gload16(Vsrc + (kt + 1) * 64, (cur == 0) ? Vd1 : Vd0);
            asm volatile("s_waitcnt vmcnt(2)" ::: "memory"); // tile kt done, kt+1 in flight
        } else {
            asm volatile("s_waitcnt vmcnt(0)" ::: "memory");
        }
        __builtin_amdgcn_s_barrier();
        const char* kb = (cur == 0) ? (const char*)Ks[0] : (const char*)Ks[1];
        const char* vb = (cur == 0) ? (const char*)Vs[0] : (const char*)Vs[1];
        if (kt * 64 <= qs + 31) { // wave active for this tile (light waves drop out early)
            const int xs = (l & 7) << 4;
            // S^T halves: s0 = kv 0..31, s1 = kv 32..63 (rows (r&3)+8(r>>2)+4hl)
            f32x16 s0 = {}, s1 = {};
            __builtin_amdgcn_s_setprio(1);
#pragma unroll
            for (int c = 0; c < 4; ++c) {
                bf16x8 kf0 = *reinterpret_cast<const bf16x8*>(kb + l31 * 128 + ((c * 32 + hl * 16) ^ xs));
                s0 = __builtin_amdgcn_mfma_f32_32x32x16_bf16(kf0, qf[c], s0, 0, 0, 0);
            }
#pragma unroll
            for (int c = 0; c < 4; ++c) {
                bf16x8 kf1 = *reinterpret_cast<const bf16x8*>(kb + (32 + l31) * 128 + ((c * 32 + hl * 16) ^ xs));
                s1 = __builtin_amdgcn_mfma_f32_32x32x16_bf16(kf1, qf[c], s1, 0, 0, 0);
            }
            __builtin_amdgcn_s_setprio(0);
            float p0[16], p1[16];
            const int ktb = kt * 64;
            const bool bnd = (ktb + 63) > qs;
            if (bnd) {
#pragma unroll
                for (int r = 0; r < 16; ++r) {
                    const int kvr = ktb + (r & 3) + 8 * (r >> 2) + 4 * hl;
                    p0[r] = (kvr > qg) ? -INFINITY : s0[r];
                    p1[r] = (kvr + 32 > qg) ? -INFINITY : s1[r];
                }
            } else {
#pragma unroll
                for (int r = 0; r < 16; ++r) { p0[r] = s0[r]; p1[r] = s1[r]; }
            }
            // row max: v_max3 tree + 1 shfl (lane l^32 holds complementary kv of same q)
            float mx[16];
#pragma unroll
            for (int r = 0; r < 16; ++r) mx[r] = fmaxf(p0[r], p1[r]);
            float u0 = max3f(mx[0], mx[1], mx[2]);
            float u1 = max3f(mx[3], mx[4], mx[5]);
            float u2 = max3f(mx[6], mx[7], mx[8]);
            float u3 = max3f(mx[9], mx[10], mx[11]);
            float u4 = max3f(mx[12], mx[13], mx[14]);
            float mt = fmaxf(max3f(u0, u1, u2), max3f(u3, u4, mx[15]));
            mt = fmaxf(mt, __shfl_xor(mt, 32));
            // defer-max (T13)
            if (!__all(mt - m_r <= 8.0f)) {
                const float mn = fmaxf(m_r, mt);
                const float al = exp2f(m_r - mn);
                m_r = mn;
                l_r *= al;
#pragma unroll
                for (int r = 0; r < 16; ++r) { o0[r] *= al; o1[r] *= al; }
            }
            float sm[16];
#pragma unroll
            for (int r = 0; r < 16; ++r) {
                p0[r] = exp2f(p0[r] - m_r);
                p1[r] = exp2f(p1[r] - m_r);
                sm[r] = p0[r] + p1[r];
            }
#pragma unroll
            for (int s2 = 8; s2 > 0; s2 >>= 1)
#pragma unroll
                for (int r = 0; r < 8; ++r) if (r < s2) sm[r] += sm[r + s2];
            l_r += sm[0] + __shfl_xor(sm[0], 32);
            // pack P: chunk m B-frag = own regs [8(m&1)..+8) of half m>>1
            u32x4 w0 = { pk2(p0[0], p0[1]), pk2(p0[2], p0[3]), pk2(p0[4], p0[5]), pk2(p0[6], p0[7]) };
            u32x4 w1 = { pk2(p0[8], p0[9]), pk2(p0[10], p0[11]), pk2(p0[12], p0[13]), pk2(p0[14], p0[15]) };
            u32x4 w2 = { pk2(p1[0], p1[1]), pk2(p1[2], p1[3]), pk2(p1[4], p1[5]), pk2(p1[6], p1[7]) };
            u32x4 w3 = { pk2(p1[8], p1[9]), pk2(p1[10], p1[11]), pk2(p1[12], p1[13]), pk2(p1[14], p1[15]) };
            bf16x8 pf0 = __builtin_bit_cast(bf16x8, w0);
            bf16x8 pf1 = __builtin_bit_cast(bf16x8, w1);
            bf16x8 pf2 = __builtin_bit_cast(bf16x8, w2);
            bf16x8 pf3 = __builtin_bit_cast(bf16x8, w3);
            // O^T += VT_psi' P : A-frag rows = hd, k-slots = permuted kv positions
            __builtin_amdgcn_s_setprio(1);
#pragma unroll
            for (int a = 0; a < 2; ++a) {
                const int rb2 = (a * 32 + l31) * 128;
                bf16x8 vf0 = *reinterpret_cast<const bf16x8*>(vb + rb2 + ((0 * 32 + hl * 16) ^ xs));
                bf16x8 vf1 = *reinterpret_cast<const bf16x8*>(vb + rb2 + ((1 * 32 + hl * 16) ^ xs));
                bf16x8 vf2 = *reinterpret_cast<const bf16x8*>(vb + rb2 + ((2 * 32 + hl * 16) ^ xs));
                bf16x8 vf3 = *reinterpret_cast<const bf16x8*>(vb + rb2 + ((3 * 32 + hl * 16) ^ xs));
                if (a == 0) {
                    o0 = __builtin_amdgcn_mfma_f32_32x32x16_bf16(vf0, pf0, o0, 0, 0, 0);
                    o0 = __builtin_amdgcn_mfma_f32_32x32x16_bf16(vf1, pf1, o0, 0, 0, 0);
                    o0 = __builtin_amdgcn_mfma_f32_32x32x16_bf16(vf2, pf2, o0, 0, 0, 0);
                    o0 = __builtin_amdgcn_mfma_f32_32x32x16_bf16(vf3, pf3, o0, 0, 0, 0);
                } else {
                    o1 = __builtin_amdgcn_mfma_f32_32x32x16_bf16(vf0, pf0, o1, 0, 0, 0);
                    o1 = __builtin_amdgcn_mfma_f32_32x32x16_bf16(vf1, pf1, o1, 0, 0, 0);
                    o1 = __builtin_amdgcn_mfma_f32_32x32x16_bf16(vf2, pf2, o1, 0, 0, 0);
                    o1 = __builtin_amdgcn_mfma_f32_32x32x16_bf16(vf3, pf3, o1, 0, 0, 0);
                }
            }
            __builtin_amdgcn_s_setprio(0);
        }
        __builtin_amdgcn_s_barrier();
        cur ^= 1;
    }
    const float inv = 1.0f / l_r;
    __bf16* ob = Ob + (size_t)(b * 2048 + qg) * 1024 + hh * 64;
#pragma unroll
    for (int gq = 0; gq < 4; ++gq) {
        bf16x4 v0 = { (__bf16)(o0[4 * gq + 0] * inv), (__bf16)(o0[4 * gq + 1] * inv),
                      (__bf16)(o0[4 * gq + 2] * inv), (__bf16)(o0[4 * gq + 3] * inv) };
        bf16x4 v1 = { (__bf16)(o1[4 * gq + 0] * inv), (__bf16)(o1[4 * gq + 1] * inv),
                      (__bf16)(o1[4 * gq + 2] * inv), (__bf16)(o1[4 * gq + 3] * inv) };
        *reinterpret_cast<bf16x4*>(ob + 8 * gq + 4 * hl) = v0;
        *reinterpret_cast<bf16x4*>(ob + 32 + 8 * gq + 4 * hl) = v1;
    }
}

extern "C" void kernel_launch(void* const* d_in, const int* in_sizes, int n_in,
                              void* d_out, int out_size, void* d_ws, size_t ws_size,
                              hipStream_t stream) {
    const float* x  = (const float*)d_in[0];
    const float* wq = (const float*)d_in[2];
    const float* bq = (const float*)d_in[3];
    const float* wk = (const float*)d_in[4];
    const float* bk = (const float*)d_in[5];
    const float* wv = (const float*)d_in[6];
    const float* bv = (const float*)d_in[7];
    const float* wo = (const float*)d_in[8];
    const float* bo = (const float*)d_in[9];
    float* out = (float*)d_out;

    char* ws = (char*)d_ws;
    __bf16* xb   = (__bf16*)(ws);                 // 8192x1024
    __bf16* wqkv = (__bf16*)(ws + 16777216);      // 3072x1024
    __bf16* wob  = (__bf16*)(ws + 23068672);      // 1024x1024
    __bf16* Qb   = (__bf16*)(ws + 25165824);      // 64x2048x64
    __bf16* Kb   = (__bf16*)(ws + 41943040);      // 64x2048x64
    __bf16* VTb  = (__bf16*)(ws + 58720256);      // 64x64x2048 (psi'-permuted)
    __bf16* Ob   = (__bf16*)(ws + 75497472);      // 8192x1024

    cast_f32_bf16<<<8192, 256, 0, stream>>>(x, xb, 2097152);
    cast_f32_bf16<<<1024, 256, 0, stream>>>(wq, wqkv, 262144);
    cast_f32_bf16<<<1024, 256, 0, stream>>>(wk, wqkv + 1048576, 262144);
    cast_f32_bf16<<<1024, 256, 0, stream>>>(wv, wqkv + 2097152, 262144);
    cast_f32_bf16<<<1024, 256, 0, stream>>>(wo, wob, 262144);

    gemm_bt<0><<<dim3(24, 64), 256, 0, stream>>>(xb, wqkv, bq, bk, bv, Qb, Kb, VTb, nullptr, 1024);
    attn_fwd<<<512, 512, 0, stream>>>(Qb, Kb, VTb, Ob);
    gemm_bt<1><<<dim3(8, 64), 256, 0, stream>>>(Ob, wob, bo, nullptr, nullptr, nullptr, nullptr, nullptr, out, 1024);
}